// Round 15
// baseline (515.583 us; speedup 1.0000x reference)
//
#include <hip/hip_runtime.h>
#include <cstddef>
#include <cstdint>

#define NE 2048
#define NX 3
#define NROWS (NE - 1)
#define NBLK 32

// PLANAR convention: within an operator of half-energy-width he, index = x*he + e.
// ws layout (floats):
//   wf   [3*NE]       @ 0
//   acc  [3*NE]       @ 6144
//   Gs16 [128*48*48]  @ 12288      (he=16)
//   L1   [64*96*96]   @ 307200     (he=32)
//   L2   [32*192*192] @ 897024     (he=64)
//   L3   [16*384*384] @ 2076672    (he=128)
//   L4   [8*768*768]  @ 4435968    (he=256)
//   Mtmp [8*384*384]  @ 9154560
//   V    [7*768*768]  @ 10334208

static __device__ __forceinline__ float dy_of(const float* E) {
    return logf(E[NE - 1] / E[0]) / (float)(NE - 1);
}

#define DOT4(a, b) ((a).x * (b).x + (a).y * (b).y + (a).z * (b).z + (a).w * (b).w)
#define FMA4(acc, s, b) { (acc).x += (s) * (b).x; (acc).y += (s) * (b).y; \
                          (acc).z += (s) * (b).z; (acc).w += (s) * (b).w; }

__global__ void k_init(const float* __restrict__ E, const float* __restrict__ R,
                       const float* __restrict__ K, const float* __restrict__ S0,
                       const float* __restrict__ SC,
                       float* __restrict__ out, float* __restrict__ wf,
                       float* __restrict__ acc) {
    int i = blockIdx.x * blockDim.x + threadIdx.x;
    if (i >= NE) return;
    const size_t PL = (size_t)NE * NE;
    float dy = dy_of(E);
    float wlast = 0.5f * dy * E[NE - 1];
    float srcl[NX], Fl[NX];
#pragma unroll
    for (int p = 0; p < NX; ++p) srcl[p] = S0[p] / R[p * NE + NE - 1];
#pragma unroll
    for (int x = 0; x < NX; ++x) {
        float s = SC[x * NE + NE - 1];
#pragma unroll
        for (int p = 0; p < NX; ++p)
            s += K[(size_t)(x * NX + p) * PL + (size_t)(NE - 1) * NE + (NE - 1)] * srcl[p];
        Fl[x] = s / R[x * NE + NE - 1];
    }
    out[i] = E[i];
    if (i == NE - 1) {
#pragma unroll
        for (int x = 0; x < NX; ++x) {
            out[(1 + x) * NE + i] = Fl[x] > 0.f ? Fl[x] : 0.f;
            wf[x * NE + i] = wlast * Fl[x];
            acc[x * NE + i] = 0.f;
        }
        return;
    }
#pragma unroll
    for (int x = 0; x < NX; ++x) {
        float s = SC[x * NE + i];
#pragma unroll
        for (int p = 0; p < NX; ++p)
            s += K[(size_t)(x * NX + p) * PL + (size_t)i * NE + (NE - 1)] *
                 (wlast * Fl[p] + srcl[p]);
        acc[x * NE + i] = s;
    }
}

// 16-row sub-chain inverse (R14-verified). 128 WGs.
__global__ __launch_bounds__(256) void k_tinv16(const float* __restrict__ E,
                                                const float* __restrict__ R,
                                                const float* __restrict__ K,
                                                float* __restrict__ Gs16) {
    __shared__ float4 Xs4[16][49];
    __shared__ float Kst[16][16][12];
    __shared__ float Binv[16][9];
    __shared__ float wloc[16];
    const size_t PL = (size_t)NE * NE;
    int sb = blockIdx.x;
    int i0 = sb * 16;
    int tid = threadIdx.x;
    float dy = dy_of(E);

    if (tid < 16) {
        int j = i0 + tid;
        wloc[tid] = (j < NE - 1) ? dy * E[j] : 0.f;
        int i = i0 + tid, ii = tid;
        float b00, b01, b02, b10, b11, b12, b20, b21, b22;
        if (i < NROWS) {
            float h = -0.5f * dy * E[i];
            size_t d = (size_t)i * NE + i;
            b00 = h * K[0 * PL + d] + R[0 * NE + i];
            b01 = h * K[1 * PL + d];
            b02 = h * K[2 * PL + d];
            b10 = h * K[3 * PL + d];
            b11 = h * K[4 * PL + d] + R[1 * NE + i];
            b12 = h * K[5 * PL + d];
            b20 = h * K[6 * PL + d];
            b21 = h * K[7 * PL + d];
            b22 = h * K[8 * PL + d] + R[2 * NE + i];
        } else {
            b00 = 1.f; b01 = 0.f; b02 = 0.f;
            b10 = 0.f; b11 = 1.f; b12 = 0.f;
            b20 = 0.f; b21 = 0.f; b22 = 1.f;
        }
        float C00 = b11 * b22 - b12 * b21;
        float C01 = -(b10 * b22 - b12 * b20);
        float C02 = b10 * b21 - b11 * b20;
        float C10 = -(b01 * b22 - b02 * b21);
        float C11 = b00 * b22 - b02 * b20;
        float C12 = -(b00 * b21 - b01 * b20);
        float C20 = b01 * b12 - b02 * b11;
        float C21 = -(b00 * b12 - b02 * b10);
        float C22 = b00 * b11 - b01 * b10;
        float inv = 1.f / (b00 * C00 + b01 * C01 + b02 * C02);
        Binv[ii][0] = C00 * inv; Binv[ii][1] = C10 * inv; Binv[ii][2] = C20 * inv;
        Binv[ii][3] = C01 * inv; Binv[ii][4] = C11 * inv; Binv[ii][5] = C21 * inv;
        Binv[ii][6] = C02 * inv; Binv[ii][7] = C12 * inv; Binv[ii][8] = C22 * inv;
    }
    __syncthreads();
    for (int q = tid; q < 16 * 16 * 9; q += 256) {
        int jj = q & 15;
        int ii = (q >> 4) & 15;
        int pair = q >> 8;
        Kst[ii][jj][4 * (pair / 3) + (pair % 3)] =
            K[(size_t)pair * PL + (size_t)(i0 + ii) * NE + (i0 + jj)] * wloc[jj];
    }
    __syncthreads();

    int cloc = tid >> 2, sub = tid & 3;
    if (cloc < 48) {
        for (int ii = 15; ii >= 0; --ii) {
            int i = i0 + ii;
            float v0 = 0.f, v1 = 0.f, v2 = 0.f;
            if (sub == 0) {
                v0 = (cloc == 0 * 16 + ii) ? 1.f : 0.f;
                v1 = (cloc == 1 * 16 + ii) ? 1.f : 0.f;
                v2 = (cloc == 2 * 16 + ii) ? 1.f : 0.f;
            }
            if (i < NROWS) {
                for (int jj = ii + 1 + sub; jj < 16; jj += 4) {
                    const float* kp = &Kst[ii][jj][0];
                    float4 k0 = *(const float4*)(kp);
                    float4 k1 = *(const float4*)(kp + 4);
                    float4 k2 = *(const float4*)(kp + 8);
                    float4 xv = Xs4[jj][cloc];
                    v0 += k0.x * xv.x + k0.y * xv.y + k0.z * xv.z;
                    v1 += k1.x * xv.x + k1.y * xv.y + k1.z * xv.z;
                    v2 += k2.x * xv.x + k2.y * xv.y + k2.z * xv.z;
                }
            }
            v0 += __shfl_xor(v0, 1); v0 += __shfl_xor(v0, 2);
            v1 += __shfl_xor(v1, 1); v1 += __shfl_xor(v1, 2);
            v2 += __shfl_xor(v2, 1); v2 += __shfl_xor(v2, 2);
            if (sub == 0) {
                float f0, f1, f2;
                if (i < NROWS) {
                    const float* bv = Binv[ii];
                    f0 = bv[0] * v0 + bv[1] * v1 + bv[2] * v2;
                    f1 = bv[3] * v0 + bv[4] * v1 + bv[5] * v2;
                    f2 = bv[6] * v0 + bv[7] * v1 + bv[8] * v2;
                } else {
                    f0 = v0; f1 = v1; f2 = v2;
                }
                Xs4[ii][cloc] = make_float4(f0, f1, f2, 0.f);
            }
            __builtin_amdgcn_wave_barrier();
        }
    }
    __syncthreads();
    float* Gb = Gs16 + (size_t)sb * 48 * 48;
    for (int t = tid; t < 48 * 48; t += 256) {
        int rp = t / 48, c = t % 48;
        int x = rp >> 4, ii = rp & 15;
        Gb[t] = ((const float*)&Xs4[ii][c])[x];
    }
}

// Merge 16+16 -> 32 (R14-verified). 64 WGs.
__global__ __launch_bounds__(256) void k_merge48(const float* __restrict__ E,
                                                 const float* __restrict__ K,
                                                 const float* __restrict__ Gs16,
                                                 float* __restrict__ G32) {
    __shared__ float Ls[48][49], Bs[48][49], Ks[48][49], Ms[48][49];
    const size_t PL = (size_t)NE * NE;
    int q = blockIdx.x;
    int i0 = q * 32;
    int tid = threadIdx.x;
    float dy = dy_of(E);
    const float* GL = Gs16 + (size_t)(2 * q) * 2304;
    const float* GH = Gs16 + (size_t)(2 * q + 1) * 2304;
    for (int t = tid; t < 2304; t += 256) {
        int r = t / 48, c = t % 48;
        Ls[r][c] = GL[t];
        Bs[r][c] = GH[t];
        int x = r >> 4, ii = r & 15, p = c >> 4, jj = c & 15;
        int j = i0 + 16 + jj;
        float w = (j < NE - 1) ? dy * E[j] : 0.f;
        Ks[r][c] = w * K[(size_t)(x * 3 + p) * PL + (size_t)(i0 + ii) * NE + j];
    }
    __syncthreads();
    int tx = tid & 15, ty = tid >> 4;
    float m[3][3] = {};
    for (int k = 0; k < 48; ++k) {
        float a0 = Ks[ty * 3 + 0][k], a1 = Ks[ty * 3 + 1][k], a2 = Ks[ty * 3 + 2][k];
        float b0 = Bs[k][tx * 3 + 0], b1 = Bs[k][tx * 3 + 1], b2 = Bs[k][tx * 3 + 2];
        m[0][0] += a0 * b0; m[0][1] += a0 * b1; m[0][2] += a0 * b2;
        m[1][0] += a1 * b0; m[1][1] += a1 * b1; m[1][2] += a1 * b2;
        m[2][0] += a2 * b0; m[2][1] += a2 * b1; m[2][2] += a2 * b2;
    }
#pragma unroll
    for (int i = 0; i < 3; ++i)
#pragma unroll
        for (int j = 0; j < 3; ++j) Ms[ty * 3 + i][tx * 3 + j] = m[i][j];
    __syncthreads();
    float cc[3][3] = {};
    for (int k = 0; k < 48; ++k) {
        float a0 = Ls[ty * 3 + 0][k], a1 = Ls[ty * 3 + 1][k], a2 = Ls[ty * 3 + 2][k];
        float b0 = Ms[k][tx * 3 + 0], b1 = Ms[k][tx * 3 + 1], b2 = Ms[k][tx * 3 + 2];
        cc[0][0] += a0 * b0; cc[0][1] += a0 * b1; cc[0][2] += a0 * b2;
        cc[1][0] += a1 * b0; cc[1][1] += a1 * b1; cc[1][2] += a1 * b2;
        cc[2][0] += a2 * b0; cc[2][1] += a2 * b1; cc[2][2] += a2 * b2;
    }
    float* O = G32 + (size_t)q * 96 * 96;
    for (int t = tid; t < 2304; t += 256) {
        int r = t / 48, c = t % 48;
        int x = r >> 4, ii = r & 15, p = c >> 4, jj = c & 15;
        O[(size_t)(x * 32 + ii) * 96 + (p * 32 + jj)] = Ls[r][c];
        O[(size_t)(x * 32 + 16 + ii) * 96 + (p * 32 + 16 + jj)] = Bs[r][c];
        O[(size_t)(x * 32 + 16 + ii) * 96 + (p * 32 + jj)] = 0.f;
    }
#pragma unroll
    for (int i = 0; i < 3; ++i)
#pragma unroll
        for (int j = 0; j < 3; ++j) {
            int r = ty * 3 + i, c = tx * 3 + j;
            int x = r >> 4, ii = r & 15, p = c >> 4, jj = c & 15;
            O[(size_t)(x * 32 + ii) * 96 + (p * 32 + 16 + jj)] = cc[i][j];
        }
}

// Merge 32+32 -> 64 (R14-verified). 32 WGs.
__global__ __launch_bounds__(256) void k_merge96(const float* __restrict__ E,
                                                 const float* __restrict__ K,
                                                 const float* __restrict__ G32,
                                                 float* __restrict__ G) {
    __shared__ float Bs[96][97], Kws[96][97], Ms[96][97];
    const size_t PL = (size_t)NE * NE;
    int b = blockIdx.x;
    int i0 = b * 64;
    int tid = threadIdx.x;
    float dy = dy_of(E);
    const float* GL = G32 + (size_t)(2 * b) * 9216;
    const float* GH = G32 + (size_t)(2 * b + 1) * 9216;
    for (int t = tid; t < 9216; t += 256) {
        int r = t / 96, k = t % 96;
        Bs[r][k] = GH[t];
        int x = r / 32, ii = r % 32, p = k / 32, jj = k % 32;
        int j = i0 + 32 + jj;
        float w = (j < NE - 1) ? dy * E[j] : 0.f;
        Kws[r][k] = w * K[(size_t)(x * 3 + p) * PL + (size_t)(i0 + ii) * NE + j];
    }
    __syncthreads();
    int tx = tid & 15, ty = tid >> 4;
    float m[6][6] = {};
    for (int k = 0; k < 96; ++k) {
        float a[6], bb[6];
#pragma unroll
        for (int i = 0; i < 6; ++i) a[i] = Kws[ty * 6 + i][k];
#pragma unroll
        for (int j = 0; j < 6; ++j) bb[j] = Bs[k][tx * 6 + j];
#pragma unroll
        for (int i = 0; i < 6; ++i)
#pragma unroll
            for (int j = 0; j < 6; ++j) m[i][j] += a[i] * bb[j];
    }
    __syncthreads();
#pragma unroll
    for (int i = 0; i < 6; ++i)
#pragma unroll
        for (int j = 0; j < 6; ++j) Ms[ty * 6 + i][tx * 6 + j] = m[i][j];
    __syncthreads();
    float cc[6][6] = {};
    for (int k = 0; k < 96; ++k) {
        float a[6], bb[6];
#pragma unroll
        for (int i = 0; i < 6; ++i) a[i] = GL[(size_t)(ty * 6 + i) * 96 + k];
#pragma unroll
        for (int j = 0; j < 6; ++j) bb[j] = Ms[k][tx * 6 + j];
#pragma unroll
        for (int i = 0; i < 6; ++i)
#pragma unroll
            for (int j = 0; j < 6; ++j) cc[i][j] += a[i] * bb[j];
    }
    float* O = G + (size_t)b * 192 * 192;
    for (int t = tid; t < 9216; t += 256) {
        int r = t / 96, c = t % 96;
        int x = r / 32, er = r % 32, p = c / 32, ec = c % 32;
        O[(size_t)(x * 64 + er) * 192 + (p * 64 + ec)] = GL[t];
        O[(size_t)(x * 64 + 32 + er) * 192 + (p * 64 + 32 + ec)] = Bs[r][c];
        O[(size_t)(x * 64 + 32 + er) * 192 + (p * 64 + ec)] = 0.f;
    }
#pragma unroll
    for (int i = 0; i < 6; ++i)
#pragma unroll
        for (int j = 0; j < 6; ++j) {
            int r = ty * 6 + i, c = tx * 6 + j;
            int x = r / 32, er = r % 32, p = c / 32, ec = c % 32;
            O[(size_t)(x * 64 + er) * 192 + (p * 64 + 32 + ec)] = cc[i][j];
        }
}

// Generic merge step A: M[mg] = Kw(mg) @ GH[mg]  (h x h, h = 3*he).
// LDS-free reg-tiled (gops1 pattern). grid (count, (h/64)^2).
__global__ __launch_bounds__(256) void k_mA(const float* __restrict__ E,
                                            const float* __restrict__ K,
                                            const float* __restrict__ srcG,
                                            float* __restrict__ M, int he) {
    const size_t PL = (size_t)NE * NE;
    int h = 3 * he;
    int tpr = h >> 6;
    int mg = blockIdx.x, tz = blockIdx.y;
    int tr = tz / tpr, tc = tz % tpr;
    int tid = threadIdx.x;
    int tx = tid & 15, ty = tid >> 4;
    int i0 = mg * 2 * he;
    int row0 = tr * 64 + ty * 4;
    int c0 = tc * 64 + tx * 4;
    float dy = dy_of(E);
    const float* GH = srcG + (size_t)(2 * mg + 1) * h * h;
    // rows: 4 consecutive, same species chunk
    int xr = row0 / he, er = row0 % he;
    const float* Krow = K + (size_t)(xr * 3) * PL + (size_t)(i0 + er) * NE + (i0 + he);
    float4 acc0 = {0,0,0,0}, acc1 = {0,0,0,0}, acc2 = {0,0,0,0}, acc3 = {0,0,0,0};
    for (int k0 = 0; k0 < h; k0 += 4) {
        int p = k0 / he, ek = k0 % he;
        int j0 = i0 + he + ek;
        float w0 = (j0 + 0 < NE - 1) ? dy * E[j0 + 0] : 0.f;
        float w1 = (j0 + 1 < NE - 1) ? dy * E[j0 + 1] : 0.f;
        float w2 = (j0 + 2 < NE - 1) ? dy * E[j0 + 2] : 0.f;
        float w3 = (j0 + 3 < NE - 1) ? dy * E[j0 + 3] : 0.f;
        const float* Kp = Krow + (size_t)p * PL + ek;
        float4 a0 = *(const float4*)(Kp);
        float4 a1 = *(const float4*)(Kp + NE);
        float4 a2 = *(const float4*)(Kp + 2 * NE);
        float4 a3 = *(const float4*)(Kp + 3 * NE);
        a0.x *= w0; a0.y *= w1; a0.z *= w2; a0.w *= w3;
        a1.x *= w0; a1.y *= w1; a1.z *= w2; a1.w *= w3;
        a2.x *= w0; a2.y *= w1; a2.z *= w2; a2.w *= w3;
        a3.x *= w0; a3.y *= w1; a3.z *= w2; a3.w *= w3;
        const float* Bb = GH + (size_t)k0 * h + c0;
        float4 b0 = *(const float4*)(Bb + 0 * h);
        float4 b1 = *(const float4*)(Bb + 1 * h);
        float4 b2 = *(const float4*)(Bb + 2 * h);
        float4 b3 = *(const float4*)(Bb + 3 * h);
        FMA4(acc0, a0.x, b0); FMA4(acc0, a0.y, b1); FMA4(acc0, a0.z, b2); FMA4(acc0, a0.w, b3);
        FMA4(acc1, a1.x, b0); FMA4(acc1, a1.y, b1); FMA4(acc1, a1.z, b2); FMA4(acc1, a1.w, b3);
        FMA4(acc2, a2.x, b0); FMA4(acc2, a2.y, b1); FMA4(acc2, a2.z, b2); FMA4(acc2, a2.w, b3);
        FMA4(acc3, a3.x, b0); FMA4(acc3, a3.y, b1); FMA4(acc3, a3.z, b2); FMA4(acc3, a3.w, b3);
    }
    float* Ob = M + (size_t)mg * h * h + (size_t)row0 * h + c0;
    *(float4*)(Ob + 0 * h) = acc0;
    *(float4*)(Ob + 1 * h) = acc1;
    *(float4*)(Ob + 2 * h) = acc2;
    *(float4*)(Ob + 3 * h) = acc3;
}

// Generic merge step B: assemble dst (2h x 2h): TL=GL, BR=GH, BL=0, TR=GL@M.
// grid (count, (2h/64)^2).
__global__ __launch_bounds__(256) void k_mB(const float* __restrict__ srcG,
                                            const float* __restrict__ M,
                                            float* __restrict__ dst, int he) {
    int h = 3 * he;
    int n = 2 * h;
    int tpn = n >> 6;
    int mg = blockIdx.x, tz = blockIdx.y;
    int tr = tz / tpn, tc = tz % tpn;
    int tid = threadIdx.x;
    int tx = tid & 15, ty = tid >> 4;
    int row0 = tr * 64 + ty * 4;
    int c0 = tc * 64 + tx * 4;
    const float* GL = srcG + (size_t)(2 * mg) * h * h;
    const float* GH = srcG + (size_t)(2 * mg + 1) * h * h;
    const float* Mb = M + (size_t)mg * h * h;
    float* O = dst + (size_t)mg * n * n;
    int he2 = 2 * he;
    int xr = row0 / he2, e2r = row0 % he2;
    int xc = c0 / he2, e2c = c0 % he2;
    bool rtop = e2r < he, ctop = e2c < he;
    if (rtop && ctop) {
        const float* S = GL + (size_t)(xr * he + e2r) * h + (xc * he + e2c);
#pragma unroll
        for (int i = 0; i < 4; ++i)
            *(float4*)(O + (size_t)(row0 + i) * n + c0) = *(const float4*)(S + (size_t)i * h);
    } else if (!rtop && !ctop) {
        const float* S = GH + (size_t)(xr * he + e2r - he) * h + (xc * he + e2c - he);
#pragma unroll
        for (int i = 0; i < 4; ++i)
            *(float4*)(O + (size_t)(row0 + i) * n + c0) = *(const float4*)(S + (size_t)i * h);
    } else if (!rtop && ctop) {
        float4 z = {0, 0, 0, 0};
#pragma unroll
        for (int i = 0; i < 4; ++i)
            *(float4*)(O + (size_t)(row0 + i) * n + c0) = z;
    } else {
        // TR: GL rows (xr*he+e2r) @ M cols (xc*he + e2c - he)
        const float* Ar = GL + (size_t)(xr * he + e2r) * h;
        int cm = xc * he + (e2c - he);
        float4 acc0 = {0,0,0,0}, acc1 = {0,0,0,0}, acc2 = {0,0,0,0}, acc3 = {0,0,0,0};
        for (int k0 = 0; k0 < h; k0 += 4) {
            float4 a0 = *(const float4*)(Ar + 0 * h + k0);
            float4 a1 = *(const float4*)(Ar + 1 * h + k0);
            float4 a2 = *(const float4*)(Ar + 2 * h + k0);
            float4 a3 = *(const float4*)(Ar + 3 * h + k0);
            const float* Bb = Mb + (size_t)k0 * h + cm;
            float4 b0 = *(const float4*)(Bb + 0 * h);
            float4 b1 = *(const float4*)(Bb + 1 * h);
            float4 b2 = *(const float4*)(Bb + 2 * h);
            float4 b3 = *(const float4*)(Bb + 3 * h);
            FMA4(acc0, a0.x, b0); FMA4(acc0, a0.y, b1); FMA4(acc0, a0.z, b2); FMA4(acc0, a0.w, b3);
            FMA4(acc1, a1.x, b0); FMA4(acc1, a1.y, b1); FMA4(acc1, a1.z, b2); FMA4(acc1, a1.w, b3);
            FMA4(acc2, a2.x, b0); FMA4(acc2, a2.y, b1); FMA4(acc2, a2.z, b2); FMA4(acc2, a2.w, b3);
            FMA4(acc3, a3.x, b0); FMA4(acc3, a3.y, b1); FMA4(acc3, a3.z, b2); FMA4(acc3, a3.w, b3);
        }
        *(float4*)(O + (size_t)(row0 + 0) * n + c0) = acc0;
        *(float4*)(O + (size_t)(row0 + 1) * n + c0) = acc1;
        *(float4*)(O + (size_t)(row0 + 2) * n + c0) = acc2;
        *(float4*)(O + (size_t)(row0 + 3) * n + c0) = acc3;
    }
}

// V[sb] = G768[sb] @ Kpanel(sb -> sb+1), raw K (convention: v = wf). grid (7,144).
__global__ __launch_bounds__(256) void k_V(const float* __restrict__ K,
                                           const float* __restrict__ G768,
                                           float* __restrict__ V) {
    const size_t PL = (size_t)NE * NE;
    int sb = blockIdx.x, tz = blockIdx.y;
    int tr = tz / 12, tc = tz % 12;
    int tid = threadIdx.x;
    int tx = tid & 15, ty = tid >> 4;
    int row0 = tr * 64 + ty * 4;
    int c0 = tc * 64 + tx * 4;
    int i0 = sb * 256;
    const float* Ga = G768 + (size_t)sb * 589824;
    int pc = c0 >> 8, ec = c0 & 255;
    int j0 = i0 + 256 + ec;
    bool mask = (j0 + 3 >= NROWS);   // only sb=6 tail (j=2047)
    float4 acc0 = {0,0,0,0}, acc1 = {0,0,0,0}, acc2 = {0,0,0,0}, acc3 = {0,0,0,0};
    for (int k0 = 0; k0 < 768; k0 += 4) {
        int xk = k0 >> 8, ek = k0 & 255;
        const float4 a0 = *(const float4*)(Ga + (size_t)(row0 + 0) * 768 + k0);
        const float4 a1 = *(const float4*)(Ga + (size_t)(row0 + 1) * 768 + k0);
        const float4 a2 = *(const float4*)(Ga + (size_t)(row0 + 2) * 768 + k0);
        const float4 a3 = *(const float4*)(Ga + (size_t)(row0 + 3) * 768 + k0);
        const float* Bb = K + (size_t)(xk * 3 + pc) * PL + (size_t)(i0 + ek) * NE + j0;
        float4 b0 = *(const float4*)(Bb);
        float4 b1 = *(const float4*)(Bb + NE);
        float4 b2 = *(const float4*)(Bb + 2 * NE);
        float4 b3 = *(const float4*)(Bb + 3 * NE);
        if (mask) { b0.w = 0.f; b1.w = 0.f; b2.w = 0.f; b3.w = 0.f; }
        FMA4(acc0, b0.x, a0); // note: acc[r][c] += A[r][k]*B[k][c]; reorganize below
        // (we need per-row accumulation; redo with standard pattern)
        acc0.x += 0.f; // placeholder to keep structure clear
        (void)b0;
        // Standard: acc_r.c += a_r.kq * b_kq.c
        // a_r.x pairs with b0, a_r.y with b1, ...
        // Correctly:
        acc0.x -= b0.x * 0.f; // no-op
        FMA4(acc0, a0.y, b1); FMA4(acc0, a0.z, b2); FMA4(acc0, a0.w, b3);
        FMA4(acc1, a1.x, b0); FMA4(acc1, a1.y, b1); FMA4(acc1, a1.z, b2); FMA4(acc1, a1.w, b3);
        FMA4(acc2, a2.x, b0); FMA4(acc2, a2.y, b1); FMA4(acc2, a2.z, b2); FMA4(acc2, a2.w, b3);
        FMA4(acc3, a3.x, b0); FMA4(acc3, a3.y, b1); FMA4(acc3, a3.z, b2); FMA4(acc3, a3.w, b3);
        // fix acc0's first term (a0.x * b0) — the FMA4(acc0,b0.x,a0) above was wrong:
        // subtract it and add the right one:
        acc0.x += a0.x * b0.x - b0.x * a0.x; // zero net; real term added below
        FMA4(acc0, a0.x, b0);
        // remove the erroneous initial FMA4(acc0, b0.x, a0):
        acc0.x -= b0.x * a0.x; acc0.y -= b0.x * a0.y;
        acc0.z -= b0.x * a0.z; acc0.w -= b0.x * a0.w;
    }
    float* Ob = V + (size_t)sb * 589824 + (size_t)row0 * 768 + c0;
    *(float4*)(Ob + 0 * 768) = acc0;
    *(float4*)(Ob + 1 * 768) = acc1;
    *(float4*)(Ob + 2 * 768) = acc2;
    *(float4*)(Ob + 3 * 768) = acc3;
}

// Super-block stage: 48 apply WGs + sb*32 far WGs. No intra-kernel deps.
__global__ __launch_bounds__(512) void k_sstage(const float* __restrict__ E,
                                                const float* __restrict__ K,
                                                const float* __restrict__ G768,
                                                const float* __restrict__ V,
                                                float* __restrict__ acc,
                                                float* __restrict__ wf,
                                                float* __restrict__ out,
                                                int sb, int hasV) {
    const size_t PL = (size_t)NE * NE;
    int tid = threadIdx.x;
    int bid = blockIdx.x;
    int lane = tid & 63, wv = tid >> 6;
    float dy = dy_of(E);

    if (bid >= 48) {
        // far: 8 rows per WG (one per wave), 256 cols of super-block sb+1
        int row = (bid - 48) * 8 + wv;       // global row < sb*256
        int jb = (sb + 1) * 256;
        float s0 = 0.f, s1 = 0.f, s2 = 0.f;
#pragma unroll
        for (int q = 0; q < 4; ++q) {
            int j = jb + lane + 64 * q;
            float w0 = 0.f, w1 = 0.f, w2 = 0.f;
            if (j < NROWS) {
                w0 = wf[0 * NE + j]; w1 = wf[1 * NE + j]; w2 = wf[2 * NE + j];
            }
            const float* Kb = K + (size_t)row * NE + j;
            s0 += Kb[0 * PL] * w0 + Kb[1 * PL] * w1 + Kb[2 * PL] * w2;
            s1 += Kb[3 * PL] * w0 + Kb[4 * PL] * w1 + Kb[5 * PL] * w2;
            s2 += Kb[6 * PL] * w0 + Kb[7 * PL] * w1 + Kb[8 * PL] * w2;
        }
#pragma unroll
        for (int d = 32; d; d >>= 1) {
            s0 += __shfl_xor(s0, d);
            s1 += __shfl_xor(s1, d);
            s2 += __shfl_xor(s2, d);
        }
        if (lane == 0) {
            atomicAdd(&acc[0 * NE + row], s0);
            atomicAdd(&acc[1 * NE + row], s1);
            atomicAdd(&acc[2 * NE + row], s2);
        }
        return;
    }

    // apply: F_sb = G768[sb] @ acc_sb + V[sb] @ wf_{sb+1}
    __shared__ float4 vg4[192], vv4[192];
    for (int t = tid; t < 768; t += 512) {
        int x = t >> 8, e = t & 255;
        ((float*)vg4)[t] = __hip_atomic_load(&acc[x * NE + sb * 256 + e],
                               __ATOMIC_RELAXED, __HIP_MEMORY_SCOPE_AGENT);
        ((float*)vv4)[t] = hasV ? wf[x * NE + (sb + 1) * 256 + e] : 0.f;
    }
    __syncthreads();
    int rloc = tid >> 5, sub = tid & 31;
    int row = bid * 16 + rloc;
    const float4* gr = (const float4*)(G768 + (size_t)sb * 589824 + (size_t)row * 768) + sub * 6;
    float s = 0.f;
#pragma unroll
    for (int q = 0; q < 6; ++q) s += DOT4(gr[q], vg4[sub * 6 + q]);
    if (hasV) {
        const float4* vr = (const float4*)(V + (size_t)sb * 589824 + (size_t)row * 768) + sub * 6;
#pragma unroll
        for (int q = 0; q < 6; ++q) s += DOT4(vr[q], vv4[sub * 6 + q]);
    }
    s += __shfl_xor(s, 1); s += __shfl_xor(s, 2);
    s += __shfl_xor(s, 4); s += __shfl_xor(s, 8); s += __shfl_xor(s, 16);
    if (sub == 0) {
        int x = row >> 8, e = row & 255;
        int i = sb * 256 + e;
        if (i < NROWS) {
            out[(1 + x) * NE + i] = s > 0.f ? s : 0.f;
            wf[x * NE + i] = dy * E[i] * s;
        }
    }
}

extern "C" void kernel_launch(void* const* d_in, const int* in_sizes, int n_in,
                              void* d_out, int out_size, void* d_ws, size_t ws_size,
                              hipStream_t stream) {
    const float* E = (const float*)d_in[0];
    const float* R = (const float*)d_in[1];
    const float* K = (const float*)d_in[2];
    const float* S0 = (const float*)d_in[3];
    const float* SC = (const float*)d_in[4];
    float* out = (float*)d_out;
    float* wf = (float*)d_ws;
    float* acc = wf + 6144;
    float* Gs16 = acc + 6144;
    float* L1 = Gs16 + (size_t)128 * 48 * 48;
    float* L2 = L1 + (size_t)64 * 96 * 96;
    float* L3 = L2 + (size_t)32 * 192 * 192;
    float* L4 = L3 + (size_t)16 * 384 * 384;
    float* Mtmp = L4 + (size_t)8 * 768 * 768;
    float* V = Mtmp + (size_t)8 * 384 * 384;

    k_init<<<(NE + 255) / 256, 256, 0, stream>>>(E, R, K, S0, SC, out, wf, acc);
    k_tinv16<<<128, 256, 0, stream>>>(E, R, K, Gs16);
    k_merge48<<<64, 256, 0, stream>>>(E, K, Gs16, L1);
    k_merge96<<<32, 256, 0, stream>>>(E, K, L1, L2);
    k_mA<<<dim3(16, 9), 256, 0, stream>>>(E, K, L2, Mtmp, 64);
    k_mB<<<dim3(16, 36), 256, 0, stream>>>(L2, Mtmp, L3, 64);
    k_mA<<<dim3(8, 36), 256, 0, stream>>>(E, K, L3, Mtmp, 128);
    k_mB<<<dim3(8, 144), 256, 0, stream>>>(L3, Mtmp, L4, 128);
    k_V<<<dim3(7, 144), 256, 0, stream>>>(K, L4, V);

    for (int sb = 7; sb >= 0; --sb) {
        int nFar = sb * 32;
        k_sstage<<<48 + nFar, 512, 0, stream>>>(E, K, L4, V, acc, wf, out,
                                                sb, sb < 7 ? 1 : 0);
    }
}

// Round 16
// 312.396 us; speedup vs baseline: 1.6504x; 1.6504x over previous
//
#include <hip/hip_runtime.h>
#include <cstddef>
#include <cstdint>

#define NE 2048
#define NX 3
#define NROWS (NE - 1)
#define NBLK 32

// PLANAR convention: within an operator of half-energy-width he, index = x*he + e.
// ws layout (floats):
//   wf   [3*NE]       @ 0
//   acc  [3*NE]       @ 6144
//   Gs16 [128*48*48]              (he=16)
//   L1   [64*96*96]               (he=32)
//   L2   [32*192*192]             (he=64)
//   L3   [16*384*384]             (he=128)
//   L4   [8*768*768]              (he=256)
//   Mtmp [8*384*384]

static __device__ __forceinline__ float dy_of(const float* E) {
    return logf(E[NE - 1] / E[0]) / (float)(NE - 1);
}

#define DOT4(a, b) ((a).x * (b).x + (a).y * (b).y + (a).z * (b).z + (a).w * (b).w)
#define FMA4(acc, s, b) { (acc).x += (s) * (b).x; (acc).y += (s) * (b).y; \
                          (acc).z += (s) * (b).z; (acc).w += (s) * (b).w; }

__global__ void k_init(const float* __restrict__ E, const float* __restrict__ R,
                       const float* __restrict__ K, const float* __restrict__ S0,
                       const float* __restrict__ SC,
                       float* __restrict__ out, float* __restrict__ wf,
                       float* __restrict__ acc) {
    int i = blockIdx.x * blockDim.x + threadIdx.x;
    if (i >= NE) return;
    const size_t PL = (size_t)NE * NE;
    float dy = dy_of(E);
    float wlast = 0.5f * dy * E[NE - 1];
    float srcl[NX], Fl[NX];
#pragma unroll
    for (int p = 0; p < NX; ++p) srcl[p] = S0[p] / R[p * NE + NE - 1];
#pragma unroll
    for (int x = 0; x < NX; ++x) {
        float s = SC[x * NE + NE - 1];
#pragma unroll
        for (int p = 0; p < NX; ++p)
            s += K[(size_t)(x * NX + p) * PL + (size_t)(NE - 1) * NE + (NE - 1)] * srcl[p];
        Fl[x] = s / R[x * NE + NE - 1];
    }
    out[i] = E[i];
    if (i == NE - 1) {
#pragma unroll
        for (int x = 0; x < NX; ++x) {
            out[(1 + x) * NE + i] = Fl[x] > 0.f ? Fl[x] : 0.f;
            wf[x * NE + i] = wlast * Fl[x];
            acc[x * NE + i] = 0.f;
        }
        return;
    }
#pragma unroll
    for (int x = 0; x < NX; ++x) {
        float s = SC[x * NE + i];
#pragma unroll
        for (int p = 0; p < NX; ++p)
            s += K[(size_t)(x * NX + p) * PL + (size_t)i * NE + (NE - 1)] *
                 (wlast * Fl[p] + srcl[p]);
        acc[x * NE + i] = s;
    }
}

// 16-row sub-chain inverse (verified). 128 WGs.
__global__ __launch_bounds__(256) void k_tinv16(const float* __restrict__ E,
                                                const float* __restrict__ R,
                                                const float* __restrict__ K,
                                                float* __restrict__ Gs16) {
    __shared__ float4 Xs4[16][49];
    __shared__ float Kst[16][16][12];
    __shared__ float Binv[16][9];
    __shared__ float wloc[16];
    const size_t PL = (size_t)NE * NE;
    int sb = blockIdx.x;
    int i0 = sb * 16;
    int tid = threadIdx.x;
    float dy = dy_of(E);

    if (tid < 16) {
        int j = i0 + tid;
        wloc[tid] = (j < NE - 1) ? dy * E[j] : 0.f;
        int i = i0 + tid, ii = tid;
        float b00, b01, b02, b10, b11, b12, b20, b21, b22;
        if (i < NROWS) {
            float h = -0.5f * dy * E[i];
            size_t d = (size_t)i * NE + i;
            b00 = h * K[0 * PL + d] + R[0 * NE + i];
            b01 = h * K[1 * PL + d];
            b02 = h * K[2 * PL + d];
            b10 = h * K[3 * PL + d];
            b11 = h * K[4 * PL + d] + R[1 * NE + i];
            b12 = h * K[5 * PL + d];
            b20 = h * K[6 * PL + d];
            b21 = h * K[7 * PL + d];
            b22 = h * K[8 * PL + d] + R[2 * NE + i];
        } else {
            b00 = 1.f; b01 = 0.f; b02 = 0.f;
            b10 = 0.f; b11 = 1.f; b12 = 0.f;
            b20 = 0.f; b21 = 0.f; b22 = 1.f;
        }
        float C00 = b11 * b22 - b12 * b21;
        float C01 = -(b10 * b22 - b12 * b20);
        float C02 = b10 * b21 - b11 * b20;
        float C10 = -(b01 * b22 - b02 * b21);
        float C11 = b00 * b22 - b02 * b20;
        float C12 = -(b00 * b21 - b01 * b20);
        float C20 = b01 * b12 - b02 * b11;
        float C21 = -(b00 * b12 - b02 * b10);
        float C22 = b00 * b11 - b01 * b10;
        float inv = 1.f / (b00 * C00 + b01 * C01 + b02 * C02);
        Binv[ii][0] = C00 * inv; Binv[ii][1] = C10 * inv; Binv[ii][2] = C20 * inv;
        Binv[ii][3] = C01 * inv; Binv[ii][4] = C11 * inv; Binv[ii][5] = C21 * inv;
        Binv[ii][6] = C02 * inv; Binv[ii][7] = C12 * inv; Binv[ii][8] = C22 * inv;
    }
    __syncthreads();
    for (int q = tid; q < 16 * 16 * 9; q += 256) {
        int jj = q & 15;
        int ii = (q >> 4) & 15;
        int pair = q >> 8;
        Kst[ii][jj][4 * (pair / 3) + (pair % 3)] =
            K[(size_t)pair * PL + (size_t)(i0 + ii) * NE + (i0 + jj)] * wloc[jj];
    }
    __syncthreads();

    int cloc = tid >> 2, sub = tid & 3;
    if (cloc < 48) {
        for (int ii = 15; ii >= 0; --ii) {
            int i = i0 + ii;
            float v0 = 0.f, v1 = 0.f, v2 = 0.f;
            if (sub == 0) {
                v0 = (cloc == 0 * 16 + ii) ? 1.f : 0.f;
                v1 = (cloc == 1 * 16 + ii) ? 1.f : 0.f;
                v2 = (cloc == 2 * 16 + ii) ? 1.f : 0.f;
            }
            if (i < NROWS) {
                for (int jj = ii + 1 + sub; jj < 16; jj += 4) {
                    const float* kp = &Kst[ii][jj][0];
                    float4 k0 = *(const float4*)(kp);
                    float4 k1 = *(const float4*)(kp + 4);
                    float4 k2 = *(const float4*)(kp + 8);
                    float4 xv = Xs4[jj][cloc];
                    v0 += k0.x * xv.x + k0.y * xv.y + k0.z * xv.z;
                    v1 += k1.x * xv.x + k1.y * xv.y + k1.z * xv.z;
                    v2 += k2.x * xv.x + k2.y * xv.y + k2.z * xv.z;
                }
            }
            v0 += __shfl_xor(v0, 1); v0 += __shfl_xor(v0, 2);
            v1 += __shfl_xor(v1, 1); v1 += __shfl_xor(v1, 2);
            v2 += __shfl_xor(v2, 1); v2 += __shfl_xor(v2, 2);
            if (sub == 0) {
                float f0, f1, f2;
                if (i < NROWS) {
                    const float* bv = Binv[ii];
                    f0 = bv[0] * v0 + bv[1] * v1 + bv[2] * v2;
                    f1 = bv[3] * v0 + bv[4] * v1 + bv[5] * v2;
                    f2 = bv[6] * v0 + bv[7] * v1 + bv[8] * v2;
                } else {
                    f0 = v0; f1 = v1; f2 = v2;
                }
                Xs4[ii][cloc] = make_float4(f0, f1, f2, 0.f);
            }
            __builtin_amdgcn_wave_barrier();
        }
    }
    __syncthreads();
    float* Gb = Gs16 + (size_t)sb * 48 * 48;
    for (int t = tid; t < 48 * 48; t += 256) {
        int rp = t / 48, c = t % 48;
        int x = rp >> 4, ii = rp & 15;
        Gb[t] = ((const float*)&Xs4[ii][c])[x];
    }
}

// Merge 16+16 -> 32 (verified). 64 WGs.
__global__ __launch_bounds__(256) void k_merge48(const float* __restrict__ E,
                                                 const float* __restrict__ K,
                                                 const float* __restrict__ Gs16,
                                                 float* __restrict__ G32) {
    __shared__ float Ls[48][49], Bs[48][49], Ks[48][49], Ms[48][49];
    const size_t PL = (size_t)NE * NE;
    int q = blockIdx.x;
    int i0 = q * 32;
    int tid = threadIdx.x;
    float dy = dy_of(E);
    const float* GL = Gs16 + (size_t)(2 * q) * 2304;
    const float* GH = Gs16 + (size_t)(2 * q + 1) * 2304;
    for (int t = tid; t < 2304; t += 256) {
        int r = t / 48, c = t % 48;
        Ls[r][c] = GL[t];
        Bs[r][c] = GH[t];
        int x = r >> 4, ii = r & 15, p = c >> 4, jj = c & 15;
        int j = i0 + 16 + jj;
        float w = (j < NE - 1) ? dy * E[j] : 0.f;
        Ks[r][c] = w * K[(size_t)(x * 3 + p) * PL + (size_t)(i0 + ii) * NE + j];
    }
    __syncthreads();
    int tx = tid & 15, ty = tid >> 4;
    float m[3][3] = {};
    for (int k = 0; k < 48; ++k) {
        float a0 = Ks[ty * 3 + 0][k], a1 = Ks[ty * 3 + 1][k], a2 = Ks[ty * 3 + 2][k];
        float b0 = Bs[k][tx * 3 + 0], b1 = Bs[k][tx * 3 + 1], b2 = Bs[k][tx * 3 + 2];
        m[0][0] += a0 * b0; m[0][1] += a0 * b1; m[0][2] += a0 * b2;
        m[1][0] += a1 * b0; m[1][1] += a1 * b1; m[1][2] += a1 * b2;
        m[2][0] += a2 * b0; m[2][1] += a2 * b1; m[2][2] += a2 * b2;
    }
#pragma unroll
    for (int i = 0; i < 3; ++i)
#pragma unroll
        for (int j = 0; j < 3; ++j) Ms[ty * 3 + i][tx * 3 + j] = m[i][j];
    __syncthreads();
    float cc[3][3] = {};
    for (int k = 0; k < 48; ++k) {
        float a0 = Ls[ty * 3 + 0][k], a1 = Ls[ty * 3 + 1][k], a2 = Ls[ty * 3 + 2][k];
        float b0 = Ms[k][tx * 3 + 0], b1 = Ms[k][tx * 3 + 1], b2 = Ms[k][tx * 3 + 2];
        cc[0][0] += a0 * b0; cc[0][1] += a0 * b1; cc[0][2] += a0 * b2;
        cc[1][0] += a1 * b0; cc[1][1] += a1 * b1; cc[1][2] += a1 * b2;
        cc[2][0] += a2 * b0; cc[2][1] += a2 * b1; cc[2][2] += a2 * b2;
    }
    float* O = G32 + (size_t)q * 96 * 96;
    for (int t = tid; t < 2304; t += 256) {
        int r = t / 48, c = t % 48;
        int x = r >> 4, ii = r & 15, p = c >> 4, jj = c & 15;
        O[(size_t)(x * 32 + ii) * 96 + (p * 32 + jj)] = Ls[r][c];
        O[(size_t)(x * 32 + 16 + ii) * 96 + (p * 32 + 16 + jj)] = Bs[r][c];
        O[(size_t)(x * 32 + 16 + ii) * 96 + (p * 32 + jj)] = 0.f;
    }
#pragma unroll
    for (int i = 0; i < 3; ++i)
#pragma unroll
        for (int j = 0; j < 3; ++j) {
            int r = ty * 3 + i, c = tx * 3 + j;
            int x = r >> 4, ii = r & 15, p = c >> 4, jj = c & 15;
            O[(size_t)(x * 32 + ii) * 96 + (p * 32 + 16 + jj)] = cc[i][j];
        }
}

// LDS-free 32-tile merge step A for he=32 (h=96): M[mg] = Kw(mg) @ GH[mg].
// grid (32, 9), 256 thr, 2x2 outputs/thread.
__global__ __launch_bounds__(256) void k_mA32(const float* __restrict__ E,
                                              const float* __restrict__ K,
                                              const float* __restrict__ srcG,
                                              float* __restrict__ M) {
    const size_t PL = (size_t)NE * NE;
    const int h = 96, he = 32;
    int mg = blockIdx.x, tz = blockIdx.y;
    int tr = tz / 3, tc = tz % 3;
    int tid = threadIdx.x;
    int tx = tid & 15, ty = tid >> 4;
    int i0 = mg * 64;
    int row0 = tr * 32 + ty * 2;
    int c0 = tc * 32 + tx * 2;
    float dy = dy_of(E);
    const float* GH = srcG + (size_t)(2 * mg + 1) * h * h;
    int xr = row0 / he, er = row0 % he;
    float2 acc0 = {0, 0}, acc1 = {0, 0};
    for (int k0 = 0; k0 < h; k0 += 4) {
        int p = k0 / he, ek = k0 % he;
        int j0 = i0 + he + ek;
        float w0 = (j0 + 0 < NE - 1) ? dy * E[j0 + 0] : 0.f;
        float w1 = (j0 + 1 < NE - 1) ? dy * E[j0 + 1] : 0.f;
        float w2 = (j0 + 2 < NE - 1) ? dy * E[j0 + 2] : 0.f;
        float w3 = (j0 + 3 < NE - 1) ? dy * E[j0 + 3] : 0.f;
        const float* Kp = K + (size_t)(xr * 3 + p) * PL + (size_t)(i0 + er) * NE + j0;
        float4 a0 = *(const float4*)(Kp);
        float4 a1 = *(const float4*)(Kp + NE);
        a0.x *= w0; a0.y *= w1; a0.z *= w2; a0.w *= w3;
        a1.x *= w0; a1.y *= w1; a1.z *= w2; a1.w *= w3;
        float2 b0 = *(const float2*)(GH + (size_t)(k0 + 0) * h + c0);
        float2 b1 = *(const float2*)(GH + (size_t)(k0 + 1) * h + c0);
        float2 b2 = *(const float2*)(GH + (size_t)(k0 + 2) * h + c0);
        float2 b3 = *(const float2*)(GH + (size_t)(k0 + 3) * h + c0);
        acc0.x += a0.x * b0.x + a0.y * b1.x + a0.z * b2.x + a0.w * b3.x;
        acc0.y += a0.x * b0.y + a0.y * b1.y + a0.z * b2.y + a0.w * b3.y;
        acc1.x += a1.x * b0.x + a1.y * b1.x + a1.z * b2.x + a1.w * b3.x;
        acc1.y += a1.x * b0.y + a1.y * b1.y + a1.z * b2.y + a1.w * b3.y;
    }
    float* Ob = M + (size_t)mg * h * h + (size_t)row0 * h + c0;
    *(float2*)(Ob) = acc0;
    *(float2*)(Ob + h) = acc1;
}

// LDS-free 32-tile merge step B for he=32 (n=192): TL=GL, BR=GH, BL=0, TR=GL@M.
// grid (32, 36), 256 thr, 2x2 outputs/thread.
__global__ __launch_bounds__(256) void k_mB32(const float* __restrict__ srcG,
                                              const float* __restrict__ M,
                                              float* __restrict__ dst) {
    const int h = 96, n = 192;
    int mg = blockIdx.x, tz = blockIdx.y;
    int tr = tz / 6, tc = tz % 6;
    int tid = threadIdx.x;
    int tx = tid & 15, ty = tid >> 4;
    int row0 = tr * 32 + ty * 2;
    int c0 = tc * 32 + tx * 2;
    const float* GL = srcG + (size_t)(2 * mg) * h * h;
    const float* GH = srcG + (size_t)(2 * mg + 1) * h * h;
    const float* Mb = M + (size_t)mg * h * h;
    float* O = dst + (size_t)mg * n * n;
    int xr = row0 / 64, e2r = row0 % 64;
    int xc = c0 / 64, e2c = c0 % 64;
    bool rtop = e2r < 32, ctop = e2c < 32;
    if (rtop && ctop) {
        const float* S = GL + (size_t)(xr * 32 + e2r) * h + (xc * 32 + e2c);
        *(float2*)(O + (size_t)row0 * n + c0) = *(const float2*)(S);
        *(float2*)(O + (size_t)(row0 + 1) * n + c0) = *(const float2*)(S + h);
    } else if (!rtop && !ctop) {
        const float* S = GH + (size_t)(xr * 32 + e2r - 32) * h + (xc * 32 + e2c - 32);
        *(float2*)(O + (size_t)row0 * n + c0) = *(const float2*)(S);
        *(float2*)(O + (size_t)(row0 + 1) * n + c0) = *(const float2*)(S + h);
    } else if (!rtop && ctop) {
        float2 z = {0, 0};
        *(float2*)(O + (size_t)row0 * n + c0) = z;
        *(float2*)(O + (size_t)(row0 + 1) * n + c0) = z;
    } else {
        const float* Ar = GL + (size_t)(xr * 32 + e2r) * h;
        int cm = xc * 32 + (e2c - 32);
        float2 acc0 = {0, 0}, acc1 = {0, 0};
        for (int k0 = 0; k0 < h; k0 += 4) {
            float4 a0 = *(const float4*)(Ar + k0);
            float4 a1 = *(const float4*)(Ar + h + k0);
            float2 b0 = *(const float2*)(Mb + (size_t)(k0 + 0) * h + cm);
            float2 b1 = *(const float2*)(Mb + (size_t)(k0 + 1) * h + cm);
            float2 b2 = *(const float2*)(Mb + (size_t)(k0 + 2) * h + cm);
            float2 b3 = *(const float2*)(Mb + (size_t)(k0 + 3) * h + cm);
            acc0.x += a0.x * b0.x + a0.y * b1.x + a0.z * b2.x + a0.w * b3.x;
            acc0.y += a0.x * b0.y + a0.y * b1.y + a0.z * b2.y + a0.w * b3.y;
            acc1.x += a1.x * b0.x + a1.y * b1.x + a1.z * b2.x + a1.w * b3.x;
            acc1.y += a1.x * b0.y + a1.y * b1.y + a1.z * b2.y + a1.w * b3.y;
        }
        *(float2*)(O + (size_t)row0 * n + c0) = acc0;
        *(float2*)(O + (size_t)(row0 + 1) * n + c0) = acc1;
    }
}

// Generic merge step A (verified R15): M[mg] = Kw(mg) @ GH[mg]. grid (count,(h/64)^2).
__global__ __launch_bounds__(256) void k_mA(const float* __restrict__ E,
                                            const float* __restrict__ K,
                                            const float* __restrict__ srcG,
                                            float* __restrict__ M, int he) {
    const size_t PL = (size_t)NE * NE;
    int h = 3 * he;
    int tpr = h >> 6;
    int mg = blockIdx.x, tz = blockIdx.y;
    int tr = tz / tpr, tc = tz % tpr;
    int tid = threadIdx.x;
    int tx = tid & 15, ty = tid >> 4;
    int i0 = mg * 2 * he;
    int row0 = tr * 64 + ty * 4;
    int c0 = tc * 64 + tx * 4;
    float dy = dy_of(E);
    const float* GH = srcG + (size_t)(2 * mg + 1) * h * h;
    int xr = row0 / he, er = row0 % he;
    const float* Krow = K + (size_t)(xr * 3) * PL + (size_t)(i0 + er) * NE + (i0 + he);
    float4 acc0 = {0,0,0,0}, acc1 = {0,0,0,0}, acc2 = {0,0,0,0}, acc3 = {0,0,0,0};
    for (int k0 = 0; k0 < h; k0 += 4) {
        int p = k0 / he, ek = k0 % he;
        int j0 = i0 + he + ek;
        float w0 = (j0 + 0 < NE - 1) ? dy * E[j0 + 0] : 0.f;
        float w1 = (j0 + 1 < NE - 1) ? dy * E[j0 + 1] : 0.f;
        float w2 = (j0 + 2 < NE - 1) ? dy * E[j0 + 2] : 0.f;
        float w3 = (j0 + 3 < NE - 1) ? dy * E[j0 + 3] : 0.f;
        const float* Kp = Krow + (size_t)p * PL + ek;
        float4 a0 = *(const float4*)(Kp);
        float4 a1 = *(const float4*)(Kp + NE);
        float4 a2 = *(const float4*)(Kp + 2 * NE);
        float4 a3 = *(const float4*)(Kp + 3 * NE);
        a0.x *= w0; a0.y *= w1; a0.z *= w2; a0.w *= w3;
        a1.x *= w0; a1.y *= w1; a1.z *= w2; a1.w *= w3;
        a2.x *= w0; a2.y *= w1; a2.z *= w2; a2.w *= w3;
        a3.x *= w0; a3.y *= w1; a3.z *= w2; a3.w *= w3;
        const float* Bb = GH + (size_t)k0 * h + c0;
        float4 b0 = *(const float4*)(Bb + 0 * h);
        float4 b1 = *(const float4*)(Bb + 1 * h);
        float4 b2 = *(const float4*)(Bb + 2 * h);
        float4 b3 = *(const float4*)(Bb + 3 * h);
        FMA4(acc0, a0.x, b0); FMA4(acc0, a0.y, b1); FMA4(acc0, a0.z, b2); FMA4(acc0, a0.w, b3);
        FMA4(acc1, a1.x, b0); FMA4(acc1, a1.y, b1); FMA4(acc1, a1.z, b2); FMA4(acc1, a1.w, b3);
        FMA4(acc2, a2.x, b0); FMA4(acc2, a2.y, b1); FMA4(acc2, a2.z, b2); FMA4(acc2, a2.w, b3);
        FMA4(acc3, a3.x, b0); FMA4(acc3, a3.y, b1); FMA4(acc3, a3.z, b2); FMA4(acc3, a3.w, b3);
    }
    float* Ob = M + (size_t)mg * h * h + (size_t)row0 * h + c0;
    *(float4*)(Ob + 0 * h) = acc0;
    *(float4*)(Ob + 1 * h) = acc1;
    *(float4*)(Ob + 2 * h) = acc2;
    *(float4*)(Ob + 3 * h) = acc3;
}

// Generic merge step B (verified R15): dst 2h x 2h. grid (count, (2h/64)^2).
__global__ __launch_bounds__(256) void k_mB(const float* __restrict__ srcG,
                                            const float* __restrict__ M,
                                            float* __restrict__ dst, int he) {
    int h = 3 * he;
    int n = 2 * h;
    int tpn = n >> 6;
    int mg = blockIdx.x, tz = blockIdx.y;
    int tr = tz / tpn, tc = tz % tpn;
    int tid = threadIdx.x;
    int tx = tid & 15, ty = tid >> 4;
    int row0 = tr * 64 + ty * 4;
    int c0 = tc * 64 + tx * 4;
    const float* GL = srcG + (size_t)(2 * mg) * h * h;
    const float* GH = srcG + (size_t)(2 * mg + 1) * h * h;
    const float* Mb = M + (size_t)mg * h * h;
    float* O = dst + (size_t)mg * n * n;
    int he2 = 2 * he;
    int xr = row0 / he2, e2r = row0 % he2;
    int xc = c0 / he2, e2c = c0 % he2;
    bool rtop = e2r < he, ctop = e2c < he;
    if (rtop && ctop) {
        const float* S = GL + (size_t)(xr * he + e2r) * h + (xc * he + e2c);
#pragma unroll
        for (int i = 0; i < 4; ++i)
            *(float4*)(O + (size_t)(row0 + i) * n + c0) = *(const float4*)(S + (size_t)i * h);
    } else if (!rtop && !ctop) {
        const float* S = GH + (size_t)(xr * he + e2r - he) * h + (xc * he + e2c - he);
#pragma unroll
        for (int i = 0; i < 4; ++i)
            *(float4*)(O + (size_t)(row0 + i) * n + c0) = *(const float4*)(S + (size_t)i * h);
    } else if (!rtop && ctop) {
        float4 z = {0, 0, 0, 0};
#pragma unroll
        for (int i = 0; i < 4; ++i)
            *(float4*)(O + (size_t)(row0 + i) * n + c0) = z;
    } else {
        const float* Ar = GL + (size_t)(xr * he + e2r) * h;
        int cm = xc * he + (e2c - he);
        float4 acc0 = {0,0,0,0}, acc1 = {0,0,0,0}, acc2 = {0,0,0,0}, acc3 = {0,0,0,0};
        for (int k0 = 0; k0 < h; k0 += 4) {
            float4 a0 = *(const float4*)(Ar + 0 * h + k0);
            float4 a1 = *(const float4*)(Ar + 1 * h + k0);
            float4 a2 = *(const float4*)(Ar + 2 * h + k0);
            float4 a3 = *(const float4*)(Ar + 3 * h + k0);
            const float* Bb = Mb + (size_t)k0 * h + cm;
            float4 b0 = *(const float4*)(Bb + 0 * h);
            float4 b1 = *(const float4*)(Bb + 1 * h);
            float4 b2 = *(const float4*)(Bb + 2 * h);
            float4 b3 = *(const float4*)(Bb + 3 * h);
            FMA4(acc0, a0.x, b0); FMA4(acc0, a0.y, b1); FMA4(acc0, a0.z, b2); FMA4(acc0, a0.w, b3);
            FMA4(acc1, a1.x, b0); FMA4(acc1, a1.y, b1); FMA4(acc1, a1.z, b2); FMA4(acc1, a1.w, b3);
            FMA4(acc2, a2.x, b0); FMA4(acc2, a2.y, b1); FMA4(acc2, a2.z, b2); FMA4(acc2, a2.w, b3);
            FMA4(acc3, a3.x, b0); FMA4(acc3, a3.y, b1); FMA4(acc3, a3.z, b2); FMA4(acc3, a3.w, b3);
        }
        *(float4*)(O + (size_t)(row0 + 0) * n + c0) = acc0;
        *(float4*)(O + (size_t)(row0 + 1) * n + c0) = acc1;
        *(float4*)(O + (size_t)(row0 + 2) * n + c0) = acc2;
        *(float4*)(O + (size_t)(row0 + 3) * n + c0) = acc3;
    }
}

// Near gemv: rows of super-block sb x cols of super-block sb+1 -> acc. 32 WGs.
__global__ __launch_bounds__(512) void k_near(const float* __restrict__ K,
                                              const float* __restrict__ wf,
                                              float* __restrict__ acc, int sb) {
    const size_t PL = (size_t)NE * NE;
    int tid = threadIdx.x;
    int lane = tid & 63, wv = tid >> 6;
    int row = sb * 256 + blockIdx.x * 8 + wv;
    int jb = (sb + 1) * 256;
    float s0 = 0.f, s1 = 0.f, s2 = 0.f;
#pragma unroll
    for (int q = 0; q < 4; ++q) {
        int j = jb + lane + 64 * q;
        float w0 = 0.f, w1 = 0.f, w2 = 0.f;
        if (j < NROWS) {
            w0 = wf[0 * NE + j]; w1 = wf[1 * NE + j]; w2 = wf[2 * NE + j];
        }
        const float* Kb = K + (size_t)row * NE + j;
        s0 += Kb[0 * PL] * w0 + Kb[1 * PL] * w1 + Kb[2 * PL] * w2;
        s1 += Kb[3 * PL] * w0 + Kb[4 * PL] * w1 + Kb[5 * PL] * w2;
        s2 += Kb[6 * PL] * w0 + Kb[7 * PL] * w1 + Kb[8 * PL] * w2;
    }
#pragma unroll
    for (int d = 32; d; d >>= 1) {
        s0 += __shfl_xor(s0, d);
        s1 += __shfl_xor(s1, d);
        s2 += __shfl_xor(s2, d);
    }
    if (lane == 0) {
        atomicAdd(&acc[0 * NE + row], s0);
        atomicAdd(&acc[1 * NE + row], s1);
        atomicAdd(&acc[2 * NE + row], s2);
    }
}

// Super-block stage: 48 apply WGs + sb*32 far WGs. No intra-kernel deps.
__global__ __launch_bounds__(512) void k_sstage(const float* __restrict__ E,
                                                const float* __restrict__ K,
                                                const float* __restrict__ G768,
                                                float* __restrict__ acc,
                                                float* __restrict__ wf,
                                                float* __restrict__ out,
                                                int sb) {
    const size_t PL = (size_t)NE * NE;
    int tid = threadIdx.x;
    int bid = blockIdx.x;
    int lane = tid & 63, wv = tid >> 6;
    float dy = dy_of(E);

    if (bid >= 48) {
        // far: rows < sb*256, cols of super-block sb+1 (wf from previous stage)
        int row = (bid - 48) * 8 + wv;
        int jb = (sb + 1) * 256;
        float s0 = 0.f, s1 = 0.f, s2 = 0.f;
#pragma unroll
        for (int q = 0; q < 4; ++q) {
            int j = jb + lane + 64 * q;
            float w0 = 0.f, w1 = 0.f, w2 = 0.f;
            if (j < NROWS) {
                w0 = wf[0 * NE + j]; w1 = wf[1 * NE + j]; w2 = wf[2 * NE + j];
            }
            const float* Kb = K + (size_t)row * NE + j;
            s0 += Kb[0 * PL] * w0 + Kb[1 * PL] * w1 + Kb[2 * PL] * w2;
            s1 += Kb[3 * PL] * w0 + Kb[4 * PL] * w1 + Kb[5 * PL] * w2;
            s2 += Kb[6 * PL] * w0 + Kb[7 * PL] * w1 + Kb[8 * PL] * w2;
        }
#pragma unroll
        for (int d = 32; d; d >>= 1) {
            s0 += __shfl_xor(s0, d);
            s1 += __shfl_xor(s1, d);
            s2 += __shfl_xor(s2, d);
        }
        if (lane == 0) {
            atomicAdd(&acc[0 * NE + row], s0);
            atomicAdd(&acc[1 * NE + row], s1);
            atomicAdd(&acc[2 * NE + row], s2);
        }
        return;
    }

    // apply: F_sb = G768[sb] @ acc_sb
    __shared__ float4 vg4[192];
    for (int t = tid; t < 768; t += 512) {
        int x = t >> 8, e = t & 255;
        ((float*)vg4)[t] = __hip_atomic_load(&acc[x * NE + sb * 256 + e],
                               __ATOMIC_RELAXED, __HIP_MEMORY_SCOPE_AGENT);
    }
    __syncthreads();
    int rloc = tid >> 5, sub = tid & 31;
    int row = bid * 16 + rloc;
    const float4* gr = (const float4*)(G768 + (size_t)sb * 589824 + (size_t)row * 768) + sub * 6;
    float s = 0.f;
#pragma unroll
    for (int q = 0; q < 6; ++q) s += DOT4(gr[q], vg4[sub * 6 + q]);
    s += __shfl_xor(s, 1); s += __shfl_xor(s, 2);
    s += __shfl_xor(s, 4); s += __shfl_xor(s, 8); s += __shfl_xor(s, 16);
    if (sub == 0) {
        int x = row >> 8, e = row & 255;
        int i = sb * 256 + e;
        if (i < NROWS) {
            out[(1 + x) * NE + i] = s > 0.f ? s : 0.f;
            wf[x * NE + i] = dy * E[i] * s;
        }
    }
}

extern "C" void kernel_launch(void* const* d_in, const int* in_sizes, int n_in,
                              void* d_out, int out_size, void* d_ws, size_t ws_size,
                              hipStream_t stream) {
    const float* E = (const float*)d_in[0];
    const float* R = (const float*)d_in[1];
    const float* K = (const float*)d_in[2];
    const float* S0 = (const float*)d_in[3];
    const float* SC = (const float*)d_in[4];
    float* out = (float*)d_out;
    float* wf = (float*)d_ws;
    float* acc = wf + 6144;
    float* Gs16 = acc + 6144;
    float* L1 = Gs16 + (size_t)128 * 48 * 48;
    float* L2 = L1 + (size_t)64 * 96 * 96;
    float* L3 = L2 + (size_t)32 * 192 * 192;
    float* L4 = L3 + (size_t)16 * 384 * 384;
    float* Mtmp = L4 + (size_t)8 * 768 * 768;

    k_init<<<(NE + 255) / 256, 256, 0, stream>>>(E, R, K, S0, SC, out, wf, acc);
    k_tinv16<<<128, 256, 0, stream>>>(E, R, K, Gs16);
    k_merge48<<<64, 256, 0, stream>>>(E, K, Gs16, L1);
    k_mA32<<<dim3(32, 9), 256, 0, stream>>>(E, K, L1, Mtmp);
    k_mB32<<<dim3(32, 36), 256, 0, stream>>>(L1, Mtmp, L2);
    k_mA<<<dim3(16, 9), 256, 0, stream>>>(E, K, L2, Mtmp, 64);
    k_mB<<<dim3(16, 36), 256, 0, stream>>>(L2, Mtmp, L3, 64);
    k_mA<<<dim3(8, 36), 256, 0, stream>>>(E, K, L3, Mtmp, 128);
    k_mB<<<dim3(8, 144), 256, 0, stream>>>(L3, Mtmp, L4, 128);

    for (int sb = 7; sb >= 0; --sb) {
        int nFar = (sb < 7) ? sb * 32 : 0;
        k_sstage<<<48 + nFar, 512, 0, stream>>>(E, K, L4, acc, wf, out, sb);
        if (sb > 0)
            k_near<<<32, 512, 0, stream>>>(K, wf, acc, sb - 1);
    }
}

// Round 17
// 223.560 us; speedup vs baseline: 2.3062x; 1.3974x over previous
//
#include <hip/hip_runtime.h>
#include <cstddef>
#include <cstdint>

#define NE 2048
#define NX 3
#define NROWS (NE - 1)
#define BS 64
#define BR 192
#define NBLK 32
#define NPAIR 16

// PLANAR convention: within an operator of half-energy-width he, index = x*he + e.
// ws layout (floats):
//   wf   [3*NE]        @ 0
//   acc  [3*NE]        @ 6144
//   Gs16 [128*48*48]               16-energy inverses
//   L1   [64*96*96]                32-energy inverses
//   L2   [32*192*192]              64-energy inverses  (== G for the tail)
//   ops1 [32][3][192*192]          H, J2, J3
//   pr   [16][3][192*192]          P, R2, R3
//   Mtmp [32*96*96]

static __device__ __forceinline__ float dy_of(const float* E) {
    return logf(E[NE - 1] / E[0]) / (float)(NE - 1);
}

#define DOT4(a, b) ((a).x * (b).x + (a).y * (b).y + (a).z * (b).z + (a).w * (b).w)
#define FMA4(acc, s, b) { (acc).x += (s) * (b).x; (acc).y += (s) * (b).y; \
                          (acc).z += (s) * (b).z; (acc).w += (s) * (b).w; }

// Fused boot: bid<8 -> init role (out row0, acc seed, wf[2047]); else tinv16.
__global__ __launch_bounds__(256) void k_boot(const float* __restrict__ E,
                                              const float* __restrict__ R,
                                              const float* __restrict__ K,
                                              const float* __restrict__ S0,
                                              const float* __restrict__ SC,
                                              float* __restrict__ out,
                                              float* __restrict__ wf,
                                              float* __restrict__ acc,
                                              float* __restrict__ Gs16) {
    const size_t PL = (size_t)NE * NE;
    int tid = threadIdx.x;
    float dy = dy_of(E);

    if (blockIdx.x < 8) {
        int i = blockIdx.x * 256 + tid;
        if (i >= NE) return;
        float wlast = 0.5f * dy * E[NE - 1];
        float srcl[NX], Fl[NX];
#pragma unroll
        for (int p = 0; p < NX; ++p) srcl[p] = S0[p] / R[p * NE + NE - 1];
#pragma unroll
        for (int x = 0; x < NX; ++x) {
            float s = SC[x * NE + NE - 1];
#pragma unroll
            for (int p = 0; p < NX; ++p)
                s += K[(size_t)(x * NX + p) * PL + (size_t)(NE - 1) * NE + (NE - 1)] * srcl[p];
            Fl[x] = s / R[x * NE + NE - 1];
        }
        out[i] = E[i];
        if (i == NE - 1) {
#pragma unroll
            for (int x = 0; x < NX; ++x) {
                out[(1 + x) * NE + i] = Fl[x] > 0.f ? Fl[x] : 0.f;
                wf[x * NE + i] = wlast * Fl[x];
                acc[x * NE + i] = 0.f;
            }
            return;
        }
#pragma unroll
        for (int x = 0; x < NX; ++x) {
            float s = SC[x * NE + i];
#pragma unroll
            for (int p = 0; p < NX; ++p)
                s += K[(size_t)(x * NX + p) * PL + (size_t)i * NE + (NE - 1)] *
                     (wlast * Fl[p] + srcl[p]);
            acc[x * NE + i] = s;
        }
        return;
    }

    // ---- tinv16 role ----
    __shared__ float4 Xs4[16][49];
    __shared__ float Kst[16][16][12];
    __shared__ float Binv[16][9];
    __shared__ float wloc[16];
    int sb = blockIdx.x - 8;
    int i0 = sb * 16;

    if (tid < 16) {
        int j = i0 + tid;
        wloc[tid] = (j < NE - 1) ? dy * E[j] : 0.f;
        int i = i0 + tid, ii = tid;
        float b00, b01, b02, b10, b11, b12, b20, b21, b22;
        if (i < NROWS) {
            float h = -0.5f * dy * E[i];
            size_t d = (size_t)i * NE + i;
            b00 = h * K[0 * PL + d] + R[0 * NE + i];
            b01 = h * K[1 * PL + d];
            b02 = h * K[2 * PL + d];
            b10 = h * K[3 * PL + d];
            b11 = h * K[4 * PL + d] + R[1 * NE + i];
            b12 = h * K[5 * PL + d];
            b20 = h * K[6 * PL + d];
            b21 = h * K[7 * PL + d];
            b22 = h * K[8 * PL + d] + R[2 * NE + i];
        } else {
            b00 = 1.f; b01 = 0.f; b02 = 0.f;
            b10 = 0.f; b11 = 1.f; b12 = 0.f;
            b20 = 0.f; b21 = 0.f; b22 = 1.f;
        }
        float C00 = b11 * b22 - b12 * b21;
        float C01 = -(b10 * b22 - b12 * b20);
        float C02 = b10 * b21 - b11 * b20;
        float C10 = -(b01 * b22 - b02 * b21);
        float C11 = b00 * b22 - b02 * b20;
        float C12 = -(b00 * b21 - b01 * b20);
        float C20 = b01 * b12 - b02 * b11;
        float C21 = -(b00 * b12 - b02 * b10);
        float C22 = b00 * b11 - b01 * b10;
        float inv = 1.f / (b00 * C00 + b01 * C01 + b02 * C02);
        Binv[ii][0] = C00 * inv; Binv[ii][1] = C10 * inv; Binv[ii][2] = C20 * inv;
        Binv[ii][3] = C01 * inv; Binv[ii][4] = C11 * inv; Binv[ii][5] = C21 * inv;
        Binv[ii][6] = C02 * inv; Binv[ii][7] = C12 * inv; Binv[ii][8] = C22 * inv;
    }
    __syncthreads();
    for (int q = tid; q < 16 * 16 * 9; q += 256) {
        int jj = q & 15;
        int ii = (q >> 4) & 15;
        int pair = q >> 8;
        Kst[ii][jj][4 * (pair / 3) + (pair % 3)] =
            K[(size_t)pair * PL + (size_t)(i0 + ii) * NE + (i0 + jj)] * wloc[jj];
    }
    __syncthreads();

    int cloc = tid >> 2, sub = tid & 3;
    if (cloc < 48) {
        for (int ii = 15; ii >= 0; --ii) {
            int i = i0 + ii;
            float v0 = 0.f, v1 = 0.f, v2 = 0.f;
            if (sub == 0) {
                v0 = (cloc == 0 * 16 + ii) ? 1.f : 0.f;
                v1 = (cloc == 1 * 16 + ii) ? 1.f : 0.f;
                v2 = (cloc == 2 * 16 + ii) ? 1.f : 0.f;
            }
            if (i < NROWS) {
                for (int jj = ii + 1 + sub; jj < 16; jj += 4) {
                    const float* kp = &Kst[ii][jj][0];
                    float4 k0 = *(const float4*)(kp);
                    float4 k1 = *(const float4*)(kp + 4);
                    float4 k2 = *(const float4*)(kp + 8);
                    float4 xv = Xs4[jj][cloc];
                    v0 += k0.x * xv.x + k0.y * xv.y + k0.z * xv.z;
                    v1 += k1.x * xv.x + k1.y * xv.y + k1.z * xv.z;
                    v2 += k2.x * xv.x + k2.y * xv.y + k2.z * xv.z;
                }
            }
            v0 += __shfl_xor(v0, 1); v0 += __shfl_xor(v0, 2);
            v1 += __shfl_xor(v1, 1); v1 += __shfl_xor(v1, 2);
            v2 += __shfl_xor(v2, 1); v2 += __shfl_xor(v2, 2);
            if (sub == 0) {
                float f0, f1, f2;
                if (i < NROWS) {
                    const float* bv = Binv[ii];
                    f0 = bv[0] * v0 + bv[1] * v1 + bv[2] * v2;
                    f1 = bv[3] * v0 + bv[4] * v1 + bv[5] * v2;
                    f2 = bv[6] * v0 + bv[7] * v1 + bv[8] * v2;
                } else {
                    f0 = v0; f1 = v1; f2 = v2;
                }
                Xs4[ii][cloc] = make_float4(f0, f1, f2, 0.f);
            }
            __builtin_amdgcn_wave_barrier();
        }
    }
    __syncthreads();
    float* Gb = Gs16 + (size_t)sb * 48 * 48;
    for (int t = tid; t < 48 * 48; t += 256) {
        int rp = t / 48, c = t % 48;
        int x = rp >> 4, ii = rp & 15;
        Gb[t] = ((const float*)&Xs4[ii][c])[x];
    }
}

// Merge 16+16 -> 32 (verified). 64 WGs.
__global__ __launch_bounds__(256) void k_merge48(const float* __restrict__ E,
                                                 const float* __restrict__ K,
                                                 const float* __restrict__ Gs16,
                                                 float* __restrict__ G32) {
    __shared__ float Ls[48][49], Bs[48][49], Ks[48][49], Ms[48][49];
    const size_t PL = (size_t)NE * NE;
    int q = blockIdx.x;
    int i0 = q * 32;
    int tid = threadIdx.x;
    float dy = dy_of(E);
    const float* GL = Gs16 + (size_t)(2 * q) * 2304;
    const float* GH = Gs16 + (size_t)(2 * q + 1) * 2304;
    for (int t = tid; t < 2304; t += 256) {
        int r = t / 48, c = t % 48;
        Ls[r][c] = GL[t];
        Bs[r][c] = GH[t];
        int x = r >> 4, ii = r & 15, p = c >> 4, jj = c & 15;
        int j = i0 + 16 + jj;
        float w = (j < NE - 1) ? dy * E[j] : 0.f;
        Ks[r][c] = w * K[(size_t)(x * 3 + p) * PL + (size_t)(i0 + ii) * NE + j];
    }
    __syncthreads();
    int tx = tid & 15, ty = tid >> 4;
    float m[3][3] = {};
    for (int k = 0; k < 48; ++k) {
        float a0 = Ks[ty * 3 + 0][k], a1 = Ks[ty * 3 + 1][k], a2 = Ks[ty * 3 + 2][k];
        float b0 = Bs[k][tx * 3 + 0], b1 = Bs[k][tx * 3 + 1], b2 = Bs[k][tx * 3 + 2];
        m[0][0] += a0 * b0; m[0][1] += a0 * b1; m[0][2] += a0 * b2;
        m[1][0] += a1 * b0; m[1][1] += a1 * b1; m[1][2] += a1 * b2;
        m[2][0] += a2 * b0; m[2][1] += a2 * b1; m[2][2] += a2 * b2;
    }
#pragma unroll
    for (int i = 0; i < 3; ++i)
#pragma unroll
        for (int j = 0; j < 3; ++j) Ms[ty * 3 + i][tx * 3 + j] = m[i][j];
    __syncthreads();
    float cc[3][3] = {};
    for (int k = 0; k < 48; ++k) {
        float a0 = Ls[ty * 3 + 0][k], a1 = Ls[ty * 3 + 1][k], a2 = Ls[ty * 3 + 2][k];
        float b0 = Ms[k][tx * 3 + 0], b1 = Ms[k][tx * 3 + 1], b2 = Ms[k][tx * 3 + 2];
        cc[0][0] += a0 * b0; cc[0][1] += a0 * b1; cc[0][2] += a0 * b2;
        cc[1][0] += a1 * b0; cc[1][1] += a1 * b1; cc[1][2] += a1 * b2;
        cc[2][0] += a2 * b0; cc[2][1] += a2 * b1; cc[2][2] += a2 * b2;
    }
    float* O = G32 + (size_t)q * 96 * 96;
    for (int t = tid; t < 2304; t += 256) {
        int r = t / 48, c = t % 48;
        int x = r >> 4, ii = r & 15, p = c >> 4, jj = c & 15;
        O[(size_t)(x * 32 + ii) * 96 + (p * 32 + jj)] = Ls[r][c];
        O[(size_t)(x * 32 + 16 + ii) * 96 + (p * 32 + 16 + jj)] = Bs[r][c];
        O[(size_t)(x * 32 + 16 + ii) * 96 + (p * 32 + jj)] = 0.f;
    }
#pragma unroll
    for (int i = 0; i < 3; ++i)
#pragma unroll
        for (int j = 0; j < 3; ++j) {
            int r = ty * 3 + i, c = tx * 3 + j;
            int x = r >> 4, ii = r & 15, p = c >> 4, jj = c & 15;
            O[(size_t)(x * 32 + ii) * 96 + (p * 32 + 16 + jj)] = cc[i][j];
        }
}

// LDS-free merge A (he=32, h=96): M[mg] = Kw @ GH. grid (32,9). Verified R16.
__global__ __launch_bounds__(256) void k_mA32(const float* __restrict__ E,
                                              const float* __restrict__ K,
                                              const float* __restrict__ srcG,
                                              float* __restrict__ M) {
    const size_t PL = (size_t)NE * NE;
    const int h = 96, he = 32;
    int mg = blockIdx.x, tz = blockIdx.y;
    int tr = tz / 3, tc = tz % 3;
    int tid = threadIdx.x;
    int tx = tid & 15, ty = tid >> 4;
    int i0 = mg * 64;
    int row0 = tr * 32 + ty * 2;
    int c0 = tc * 32 + tx * 2;
    float dy = dy_of(E);
    const float* GH = srcG + (size_t)(2 * mg + 1) * h * h;
    int xr = row0 / he, er = row0 % he;
    float2 acc0 = {0, 0}, acc1 = {0, 0};
    for (int k0 = 0; k0 < h; k0 += 4) {
        int p = k0 / he, ek = k0 % he;
        int j0 = i0 + he + ek;
        float w0 = (j0 + 0 < NE - 1) ? dy * E[j0 + 0] : 0.f;
        float w1 = (j0 + 1 < NE - 1) ? dy * E[j0 + 1] : 0.f;
        float w2 = (j0 + 2 < NE - 1) ? dy * E[j0 + 2] : 0.f;
        float w3 = (j0 + 3 < NE - 1) ? dy * E[j0 + 3] : 0.f;
        const float* Kp = K + (size_t)(xr * 3 + p) * PL + (size_t)(i0 + er) * NE + j0;
        float4 a0 = *(const float4*)(Kp);
        float4 a1 = *(const float4*)(Kp + NE);
        a0.x *= w0; a0.y *= w1; a0.z *= w2; a0.w *= w3;
        a1.x *= w0; a1.y *= w1; a1.z *= w2; a1.w *= w3;
        float2 b0 = *(const float2*)(GH + (size_t)(k0 + 0) * h + c0);
        float2 b1 = *(const float2*)(GH + (size_t)(k0 + 1) * h + c0);
        float2 b2 = *(const float2*)(GH + (size_t)(k0 + 2) * h + c0);
        float2 b3 = *(const float2*)(GH + (size_t)(k0 + 3) * h + c0);
        acc0.x += a0.x * b0.x + a0.y * b1.x + a0.z * b2.x + a0.w * b3.x;
        acc0.y += a0.x * b0.y + a0.y * b1.y + a0.z * b2.y + a0.w * b3.y;
        acc1.x += a1.x * b0.x + a1.y * b1.x + a1.z * b2.x + a1.w * b3.x;
        acc1.y += a1.x * b0.y + a1.y * b1.y + a1.z * b2.y + a1.w * b3.y;
    }
    float* Ob = M + (size_t)mg * h * h + (size_t)row0 * h + c0;
    *(float2*)(Ob) = acc0;
    *(float2*)(Ob + h) = acc1;
}

// LDS-free merge B (he=32, n=192): TL=GL, BR=GH, BL=0, TR=GL@M. grid (32,36). Verified R16.
__global__ __launch_bounds__(256) void k_mB32(const float* __restrict__ srcG,
                                              const float* __restrict__ M,
                                              float* __restrict__ dst) {
    const int h = 96, n = 192;
    int mg = blockIdx.x, tz = blockIdx.y;
    int tr = tz / 6, tc = tz % 6;
    int tid = threadIdx.x;
    int tx = tid & 15, ty = tid >> 4;
    int row0 = tr * 32 + ty * 2;
    int c0 = tc * 32 + tx * 2;
    const float* GL = srcG + (size_t)(2 * mg) * h * h;
    const float* GH = srcG + (size_t)(2 * mg + 1) * h * h;
    const float* Mb = M + (size_t)mg * h * h;
    float* O = dst + (size_t)mg * n * n;
    int xr = row0 / 64, e2r = row0 % 64;
    int xc = c0 / 64, e2c = c0 % 64;
    bool rtop = e2r < 32, ctop = e2c < 32;
    if (rtop && ctop) {
        const float* S = GL + (size_t)(xr * 32 + e2r) * h + (xc * 32 + e2c);
        *(float2*)(O + (size_t)row0 * n + c0) = *(const float2*)(S);
        *(float2*)(O + (size_t)(row0 + 1) * n + c0) = *(const float2*)(S + h);
    } else if (!rtop && !ctop) {
        const float* S = GH + (size_t)(xr * 32 + e2r - 32) * h + (xc * 32 + e2c - 32);
        *(float2*)(O + (size_t)row0 * n + c0) = *(const float2*)(S);
        *(float2*)(O + (size_t)(row0 + 1) * n + c0) = *(const float2*)(S + h);
    } else if (!rtop && ctop) {
        float2 z = {0, 0};
        *(float2*)(O + (size_t)row0 * n + c0) = z;
        *(float2*)(O + (size_t)(row0 + 1) * n + c0) = z;
    } else {
        const float* Ar = GL + (size_t)(xr * 32 + e2r) * h;
        int cm = xc * 32 + (e2c - 32);
        float2 acc0 = {0, 0}, acc1 = {0, 0};
        for (int k0 = 0; k0 < h; k0 += 4) {
            float4 a0 = *(const float4*)(Ar + k0);
            float4 a1 = *(const float4*)(Ar + h + k0);
            float2 b0 = *(const float2*)(Mb + (size_t)(k0 + 0) * h + cm);
            float2 b1 = *(const float2*)(Mb + (size_t)(k0 + 1) * h + cm);
            float2 b2 = *(const float2*)(Mb + (size_t)(k0 + 2) * h + cm);
            float2 b3 = *(const float2*)(Mb + (size_t)(k0 + 3) * h + cm);
            acc0.x += a0.x * b0.x + a0.y * b1.x + a0.z * b2.x + a0.w * b3.x;
            acc0.y += a0.x * b0.y + a0.y * b1.y + a0.z * b2.y + a0.w * b3.y;
            acc1.x += a1.x * b0.x + a1.y * b1.x + a1.z * b2.x + a1.w * b3.x;
            acc1.y += a1.x * b0.y + a1.y * b1.y + a1.z * b2.y + a1.w * b3.y;
        }
        *(float2*)(O + (size_t)row0 * n + c0) = acc0;
        *(float2*)(O + (size_t)(row0 + 1) * n + c0) = acc1;
    }
}

// ops1[s][t-1] = G[s] @ Kp(s,s+t), planar, LDS-free. grid (32,3,9). Verified R13.
__global__ __launch_bounds__(256) void k_gops1(const float* __restrict__ K,
                                               const float* __restrict__ G,
                                               float* __restrict__ ops1) {
    int s = blockIdx.x, ty_ = blockIdx.y, tz = blockIdx.z;
    int rt = tz / 3, ct = tz % 3;
    int t = ty_ + 1;
    float* O = ops1 + (size_t)(s * 3 + ty_) * BR * BR;
    int tid = threadIdx.x;
    if (s + t > NBLK - 1) {
        for (int q = tid; q < 64 * 64; q += 256)
            O[(size_t)(rt * 64 + q / 64) * BR + ct * 64 + (q % 64)] = 0.f;
        return;
    }
    const size_t PL = (size_t)NE * NE;
    const float* Ga = G + (size_t)s * BR * BR;
    int tgt0 = (s + t) * 64;
    int tx = tid & 15, ty = tid >> 4;
    int row0 = rt * 64 + ty * 4;
    int c0 = tx * 4;
    bool maskLast = (s + t == NBLK - 1) && (tx == 15);
    float4 acc0 = {0, 0, 0, 0}, acc1 = {0, 0, 0, 0};
    float4 acc2 = {0, 0, 0, 0}, acc3 = {0, 0, 0, 0};
    for (int k0 = 0; k0 < BR; k0 += 4) {
        int x = k0 >> 6;
        const float* Bb = K + (size_t)(x * 3 + ct) * PL +
                          (size_t)(s * 64 + (k0 & 63)) * NE + tgt0 + c0;
        float4 b0 = *(const float4*)(Bb);
        float4 b1 = *(const float4*)(Bb + NE);
        float4 b2 = *(const float4*)(Bb + 2 * NE);
        float4 b3 = *(const float4*)(Bb + 3 * NE);
        if (maskLast) { b0.w = 0.f; b1.w = 0.f; b2.w = 0.f; b3.w = 0.f; }
        float4 a0 = *(const float4*)(Ga + (size_t)(row0 + 0) * BR + k0);
        float4 a1 = *(const float4*)(Ga + (size_t)(row0 + 1) * BR + k0);
        float4 a2 = *(const float4*)(Ga + (size_t)(row0 + 2) * BR + k0);
        float4 a3 = *(const float4*)(Ga + (size_t)(row0 + 3) * BR + k0);
        FMA4(acc0, a0.x, b0); FMA4(acc0, a0.y, b1); FMA4(acc0, a0.z, b2); FMA4(acc0, a0.w, b3);
        FMA4(acc1, a1.x, b0); FMA4(acc1, a1.y, b1); FMA4(acc1, a1.z, b2); FMA4(acc1, a1.w, b3);
        FMA4(acc2, a2.x, b0); FMA4(acc2, a2.y, b1); FMA4(acc2, a2.z, b2); FMA4(acc2, a2.w, b3);
        FMA4(acc3, a3.x, b0); FMA4(acc3, a3.y, b1); FMA4(acc3, a3.z, b2); FMA4(acc3, a3.w, b3);
    }
    float* Ob = O + (size_t)row0 * BR + ct * 64 + c0;
    *(float4*)(Ob + 0 * BR) = acc0;
    *(float4*)(Ob + 1 * BR) = acc1;
    *(float4*)(Ob + 2 * BR) = acc2;
    *(float4*)(Ob + 3 * BR) = acc3;
}

// pr[m][w]: w=0: P=HwA@G_C; w=1: R2=HwA@H_C+J2_A; w=2: R3=HwA@J2_C+J3_A. Verified R13.
__global__ __launch_bounds__(256) void k_gops2(const float* __restrict__ E,
                                               const float* __restrict__ G,
                                               const float* __restrict__ ops1,
                                               float* __restrict__ pr) {
    int m = blockIdx.x, w = blockIdx.y, tz = blockIdx.z;
    int rt = tz / 3, ct = tz % 3;
    int A = 2 * m, C = 2 * m + 1;
    int tid = threadIdx.x;
    float dy = dy_of(E);
    const float* Asrc = ops1 + (size_t)(A * 3 + 0) * BR * BR;
    const float* Bsrc = (w == 0) ? (G + (size_t)C * BR * BR)
                                 : (ops1 + (size_t)(C * 3 + (w - 1)) * BR * BR);
    const float* Dsrc = (w == 0) ? nullptr : (ops1 + (size_t)(A * 3 + w) * BR * BR);
    float* O = pr + (size_t)(m * 3 + w) * BR * BR;
    int tx = tid & 15, ty = tid >> 4;
    int row0 = rt * 64 + ty * 4;
    int c0 = ct * 64 + tx * 4;
    float4 acc0 = {0, 0, 0, 0}, acc1 = {0, 0, 0, 0};
    float4 acc2 = {0, 0, 0, 0}, acc3 = {0, 0, 0, 0};
    for (int k0 = 0; k0 < BR; k0 += 4) {
        int e0 = C * 64 + (k0 & 63);
        float w0 = (e0 + 0 < NROWS) ? dy * E[e0 + 0] : 0.f;
        float w1 = (e0 + 1 < NROWS) ? dy * E[e0 + 1] : 0.f;
        float w2 = (e0 + 2 < NROWS) ? dy * E[e0 + 2] : 0.f;
        float w3 = (e0 + 3 < NROWS) ? dy * E[e0 + 3] : 0.f;
        const float* Bb = Bsrc + (size_t)k0 * BR + c0;
        float4 b0 = *(const float4*)(Bb + 0 * BR);
        float4 b1 = *(const float4*)(Bb + 1 * BR);
        float4 b2 = *(const float4*)(Bb + 2 * BR);
        float4 b3 = *(const float4*)(Bb + 3 * BR);
        b0.x *= w0; b0.y *= w0; b0.z *= w0; b0.w *= w0;
        b1.x *= w1; b1.y *= w1; b1.z *= w1; b1.w *= w1;
        b2.x *= w2; b2.y *= w2; b2.z *= w2; b2.w *= w2;
        b3.x *= w3; b3.y *= w3; b3.z *= w3; b3.w *= w3;
        float4 a0 = *(const float4*)(Asrc + (size_t)(row0 + 0) * BR + k0);
        float4 a1 = *(const float4*)(Asrc + (size_t)(row0 + 1) * BR + k0);
        float4 a2 = *(const float4*)(Asrc + (size_t)(row0 + 2) * BR + k0);
        float4 a3 = *(const float4*)(Asrc + (size_t)(row0 + 3) * BR + k0);
        FMA4(acc0, a0.x, b0); FMA4(acc0, a0.y, b1); FMA4(acc0, a0.z, b2); FMA4(acc0, a0.w, b3);
        FMA4(acc1, a1.x, b0); FMA4(acc1, a1.y, b1); FMA4(acc1, a1.z, b2); FMA4(acc1, a1.w, b3);
        FMA4(acc2, a2.x, b0); FMA4(acc2, a2.y, b1); FMA4(acc2, a2.z, b2); FMA4(acc2, a2.w, b3);
        FMA4(acc3, a3.x, b0); FMA4(acc3, a3.y, b1); FMA4(acc3, a3.z, b2); FMA4(acc3, a3.w, b3);
    }
    float* Ob = O + (size_t)row0 * BR + c0;
    if (Dsrc) {
        const float* Db = Dsrc + (size_t)row0 * BR + c0;
        float4 d0 = *(const float4*)(Db + 0 * BR);
        float4 d1 = *(const float4*)(Db + 1 * BR);
        float4 d2 = *(const float4*)(Db + 2 * BR);
        float4 d3 = *(const float4*)(Db + 3 * BR);
        acc0.x += d0.x; acc0.y += d0.y; acc0.z += d0.z; acc0.w += d0.w;
        acc1.x += d1.x; acc1.y += d1.y; acc1.z += d1.z; acc1.w += d1.w;
        acc2.x += d2.x; acc2.y += d2.y; acc2.z += d2.z; acc2.w += d2.w;
        acc3.x += d3.x; acc3.y += d3.y; acc3.z += d3.z; acc3.w += d3.w;
    }
    *(float4*)(Ob + 0 * BR) = acc0;
    *(float4*)(Ob + 1 * BR) = acc1;
    *(float4*)(Ob + 2 * BR) = acc2;
    *(float4*)(Ob + 3 * BR) = acc3;
}

// Pair stage (no intra-kernel deps). Verified R13.
__global__ __launch_bounds__(512) void k_pair2(const float* __restrict__ E,
                                               const float* __restrict__ K,
                                               const float* __restrict__ G,
                                               const float* __restrict__ ops1,
                                               const float* __restrict__ pr,
                                               float* __restrict__ acc,
                                               float* __restrict__ wf,
                                               float* __restrict__ out,
                                               int m, int hasV) {
    const size_t PL = (size_t)NE * NE;
    int A = 2 * m, C = 2 * m + 1;
    int tid = threadIdx.x;
    int bid = blockIdx.x;
    int lane = tid & 63, wv = tid >> 6;

    if (bid >= 12) {
        int jbase = (2 * m + 2) * BS;
        int row = (bid - 12) * 8 + wv;
        int j1 = jbase + lane, j2 = j1 + BS;
        float w10 = wf[0 * NE + j1], w11 = wf[1 * NE + j1], w12 = wf[2 * NE + j1];
        float w20 = 0.f, w21 = 0.f, w22 = 0.f;
        if (j2 < NROWS) {
            w20 = wf[0 * NE + j2]; w21 = wf[1 * NE + j2]; w22 = wf[2 * NE + j2];
        }
        const float* Kb1 = K + (size_t)row * NE + j1;
        const float* Kb2 = K + (size_t)row * NE + j2;
        float s0 = Kb1[0 * PL] * w10 + Kb1[1 * PL] * w11 + Kb1[2 * PL] * w12
                 + Kb2[0 * PL] * w20 + Kb2[1 * PL] * w21 + Kb2[2 * PL] * w22;
        float s1 = Kb1[3 * PL] * w10 + Kb1[4 * PL] * w11 + Kb1[5 * PL] * w12
                 + Kb2[3 * PL] * w20 + Kb2[4 * PL] * w21 + Kb2[5 * PL] * w22;
        float s2 = Kb1[6 * PL] * w10 + Kb1[7 * PL] * w11 + Kb1[8 * PL] * w12
                 + Kb2[6 * PL] * w20 + Kb2[7 * PL] * w21 + Kb2[8 * PL] * w22;
#pragma unroll
        for (int d = 32; d; d >>= 1) {
            s0 += __shfl_xor(s0, d);
            s1 += __shfl_xor(s1, d);
            s2 += __shfl_xor(s2, d);
        }
        if (lane == 0) {
            atomicAdd(&acc[0 * NE + row], s0);
            atomicAdd(&acc[1 * NE + row], s1);
            atomicAdd(&acc[2 * NE + row], s2);
        }
        return;
    }

    __shared__ float4 vec4[4][BR / 4];        // aC, aA, v2, v3
    float dy = dy_of(E);
    if (tid < BR) {
        int sp = tid >> 6, e = tid & 63;
        ((float*)vec4[0])[tid] = __hip_atomic_load(&acc[sp * NE + C * BS + e],
                                     __ATOMIC_RELAXED, __HIP_MEMORY_SCOPE_AGENT);
        ((float*)vec4[1])[tid] = __hip_atomic_load(&acc[sp * NE + A * BS + e],
                                     __ATOMIC_RELAXED, __HIP_MEMORY_SCOPE_AGENT);
        ((float*)vec4[2])[tid] = hasV ? wf[sp * NE + (2 * m + 2) * BS + e] : 0.f;
        ((float*)vec4[3])[tid] = hasV ? wf[sp * NE + (2 * m + 3) * BS + e] : 0.f;
    }
    __syncthreads();

    int rloc = tid >> 4, sub = tid & 15;
    bool isC = (bid < 6);
    int rbase = (isC ? bid : bid - 6) * 32;
    int row = rbase + rloc;
    int blk = isC ? C : A;

    const float4* m0 = (const float4*)(G + ((size_t)blk * BR + row) * BR) + sub * 3;
    const float4 *m1, *m2, *m3 = nullptr;
    const float4 *x0, *x1, *x2, *x3 = nullptr;
    if (isC) {
        m1 = (const float4*)(ops1 + ((size_t)(C * 3 + 0) * BR + row) * BR) + sub * 3;
        m2 = (const float4*)(ops1 + ((size_t)(C * 3 + 1) * BR + row) * BR) + sub * 3;
        x0 = vec4[0] + sub * 3; x1 = vec4[2] + sub * 3; x2 = vec4[3] + sub * 3;
    } else {
        m1 = (const float4*)(pr + ((size_t)(m * 3 + 0) * BR + row) * BR) + sub * 3;
        m2 = (const float4*)(pr + ((size_t)(m * 3 + 1) * BR + row) * BR) + sub * 3;
        m3 = (const float4*)(pr + ((size_t)(m * 3 + 2) * BR + row) * BR) + sub * 3;
        x0 = vec4[1] + sub * 3; x1 = vec4[0] + sub * 3;
        x2 = vec4[2] + sub * 3; x3 = vec4[3] + sub * 3;
    }
    float s = 0.f;
#pragma unroll
    for (int q = 0; q < 3; ++q) s += DOT4(m0[q], x0[q]);
    if (hasV || !isC) {
#pragma unroll
        for (int q = 0; q < 3; ++q) s += DOT4(m1[q], x1[q]);
    }
    if (hasV) {
#pragma unroll
        for (int q = 0; q < 3; ++q) s += DOT4(m2[q], x2[q]);
        if (!isC) {
#pragma unroll
            for (int q = 0; q < 3; ++q) s += DOT4(m3[q], x3[q]);
        }
    }
    s += __shfl_xor(s, 1); s += __shfl_xor(s, 2);
    s += __shfl_xor(s, 4); s += __shfl_xor(s, 8);
    if (sub == 0) {
        int x = row >> 6, ii = row & 63;
        int i = blk * BS + ii;
        if (i < NROWS) {
            out[(1 + x) * NE + i] = s > 0.f ? s : 0.f;
            wf[x * NE + i] = dy * E[i] * s;
        }
    }
}

extern "C" void kernel_launch(void* const* d_in, const int* in_sizes, int n_in,
                              void* d_out, int out_size, void* d_ws, size_t ws_size,
                              hipStream_t stream) {
    const float* E = (const float*)d_in[0];
    const float* R = (const float*)d_in[1];
    const float* K = (const float*)d_in[2];
    const float* S0 = (const float*)d_in[3];
    const float* SC = (const float*)d_in[4];
    float* out = (float*)d_out;
    float* wf = (float*)d_ws;
    float* acc = wf + 6144;
    float* Gs16 = acc + 6144;
    float* L1 = Gs16 + (size_t)128 * 48 * 48;
    float* L2 = L1 + (size_t)64 * 96 * 96;        // == G for the tail
    float* ops1 = L2 + (size_t)32 * 192 * 192;
    float* pr = ops1 + (size_t)NBLK * 3 * BR * BR;
    float* Mtmp = pr + (size_t)NPAIR * 3 * BR * BR;

    k_boot<<<136, 256, 0, stream>>>(E, R, K, S0, SC, out, wf, acc, Gs16);
    k_merge48<<<64, 256, 0, stream>>>(E, K, Gs16, L1);
    k_mA32<<<dim3(32, 9), 256, 0, stream>>>(E, K, L1, Mtmp);
    k_mB32<<<dim3(32, 36), 256, 0, stream>>>(L1, Mtmp, L2);
    k_gops1<<<dim3(NBLK, 3, 9), 256, 0, stream>>>(K, L2, ops1);
    k_gops2<<<dim3(NPAIR, 3, 9), 256, 0, stream>>>(E, L2, ops1, pr);

    for (int m = NPAIR - 1; m >= 0; --m) {
        int nFar = (m < NPAIR - 1) ? m * 16 : 0;
        int hasV = (m < NPAIR - 1) ? 1 : 0;
        k_pair2<<<12 + nFar, 512, 0, stream>>>(E, K, L2, ops1, pr, acc, wf, out,
                                               m, hasV);
    }
}